// Round 1
// baseline (1809.906 us; speedup 1.0000x reference)
//
#include <hip/hip_runtime.h>
#include <hip/hip_bf16.h>
#include <math.h>

#define TT 2048
#define CC 1024
#define HH 16
#define DDIM 64
#define MM 8192
#define C3 3072

#define LTPAIR(sa,ma,sb,mb) ((sa) < (sb) || ((sa) == (sb) && (ma) < (mb)))

__device__ __forceinline__ float waveReduceSum(float v) {
#pragma unroll
  for (int off = 32; off > 0; off >>= 1) v += __shfl_xor(v, off, 64);
  return v;
}

// C[i][j] = sum_k A[i][k] * B[j][k]   (A: Mr x Kd row-major, B: Nc x Kd row-major)
__global__ __launch_bounds__(256) void gemm_nt_f32(
    const float* __restrict__ A, const float* __restrict__ B,
    float* __restrict__ Cmat, int Mr, int Nc, int Kd)
{
  __shared__ float As[32][65];
  __shared__ float Bs[32][65];
  const int tid = threadIdx.x;
  const int tx = tid & 15, ty = tid >> 4;
  const float* Ab = A + (size_t)blockIdx.y * 64 * Kd;
  const float* Bb = B + (size_t)blockIdx.x * 64 * Kd;
  float acc[4][4] = {{0.f,0.f,0.f,0.f},{0.f,0.f,0.f,0.f},{0.f,0.f,0.f,0.f},{0.f,0.f,0.f,0.f}};
  for (int k0 = 0; k0 < Kd; k0 += 32) {
#pragma unroll
    for (int r = 0; r < 8; ++r) {
      int e = tid + r * 256;
      int row = e >> 5, kk = e & 31;
      As[kk][row] = Ab[(size_t)row * Kd + k0 + kk];
      Bs[kk][row] = Bb[(size_t)row * Kd + k0 + kk];
    }
    __syncthreads();
#pragma unroll 8
    for (int kk = 0; kk < 32; ++kk) {
      float a[4], b[4];
#pragma unroll
      for (int i = 0; i < 4; ++i) a[i] = As[kk][ty*4+i];
#pragma unroll
      for (int j = 0; j < 4; ++j) b[j] = Bs[kk][tx*4+j];
#pragma unroll
      for (int i = 0; i < 4; ++i)
#pragma unroll
        for (int j = 0; j < 4; ++j) acc[i][j] += a[i]*b[j];
    }
    __syncthreads();
  }
#pragma unroll
  for (int i = 0; i < 4; ++i)
#pragma unroll
    for (int j = 0; j < 4; ++j)
      Cmat[(size_t)(blockIdx.y*64 + ty*4 + i) * Nc + blockIdx.x*64 + tx*4 + j] = acc[i][j];
}

__global__ __launch_bounds__(256) void sqnorm_k(const float* __restrict__ ks, float* __restrict__ ksn)
{
  int r = blockIdx.x * 256 + threadIdx.x;
  if (r >= HH*MM) return;
  const float4* p = (const float4*)(ks + (size_t)r * DDIM);
  float s = 0.f;
#pragma unroll
  for (int i = 0; i < 16; ++i) { float4 v = p[i]; s += v.x*v.x + v.y*v.y + v.z*v.z + v.w*v.w; }
  ksn[r] = s;
}

// exact fp32 softmax of last attention row -> mask bits
__global__ __launch_bounds__(256) void attlast_mask_k(const float* __restrict__ qkv, int* __restrict__ mask)
{
  const int h = blockIdx.x;
  __shared__ float ql[64];
  __shared__ float lg[TT];
  __shared__ float red[256];
  const int tid = threadIdx.x;
  if (tid < 64) ql[tid] = qkv[(size_t)(TT-1)*C3 + h*DDIM + tid];
  __syncthreads();
  float lmax = -INFINITY;
  for (int t = tid; t < TT; t += 256) {
    const float* kr = qkv + (size_t)t*C3 + CC + h*DDIM;
    float s = 0.f;
#pragma unroll
    for (int d = 0; d < 64; ++d) s += ql[d] * kr[d];
    s *= 0.125f;
    lg[t] = s;
    lmax = fmaxf(lmax, s);
  }
  red[tid] = lmax; __syncthreads();
  for (int off = 128; off > 0; off >>= 1) { if (tid < off) red[tid] = fmaxf(red[tid], red[tid+off]); __syncthreads(); }
  float mx = red[0];
  __syncthreads();
  float ls = 0.f;
  for (int t = tid; t < TT; t += 256) { float e = expf(lg[t]-mx); lg[t] = e; ls += e; }
  red[tid] = ls; __syncthreads();
  for (int off = 128; off > 0; off >>= 1) { if (tid < off) red[tid] += red[tid+off]; __syncthreads(); }
  float Z = red[0];
  for (int t = tid; t < TT; t += 256) mask[h*TT + t] = (lg[t]/Z >= 1.220703125e-4f) ? 1 : 0;
}

// fused score + top-4 per (h, n): score = |ks_m|^2 - 2*k_n.ks_m  (|k_n|^2 is rank-invariant)
__global__ __launch_bounds__(256) void knn_topk_k(
    const float* __restrict__ qkv, const float* __restrict__ kstore,
    const float* __restrict__ ksn, int* __restrict__ idxout)
{
  __shared__ float smem[2*64*65];
  float* khs = smem;           // [64][65]
  float* kss = smem + 64*65;   // [64][65]
  const int h = blockIdx.y;
  const int n0 = blockIdx.x * 64;
  const int tid = threadIdx.x;
  const int tx = tid & 15, ty = tid >> 4;
#pragma unroll
  for (int r = 0; r < 16; ++r) {
    int e = tid + r*256;
    int row = e >> 6, d = e & 63;
    khs[row*65 + d] = qkv[(size_t)(n0+row)*C3 + CC + h*DDIM + d];
  }
  float bs[4][4]; int bm[4][4];
#pragma unroll
  for (int i = 0; i < 4; ++i)
#pragma unroll
    for (int c = 0; c < 4; ++c) { bs[i][c] = 3.4e38f; bm[i][c] = 0x7fffffff; }
  const float* ksb = kstore + (size_t)h*MM*DDIM;
  const float* ksnb = ksn + h*MM;
  for (int m0 = 0; m0 < MM; m0 += 64) {
    __syncthreads();
#pragma unroll
    for (int r = 0; r < 16; ++r) {
      int e = tid + r*256;
      int row = e >> 6, d = e & 63;
      kss[row*65 + d] = ksb[(size_t)(m0+row)*DDIM + d];
    }
    __syncthreads();
    float acc[4][4] = {{0.f,0.f,0.f,0.f},{0.f,0.f,0.f,0.f},{0.f,0.f,0.f,0.f},{0.f,0.f,0.f,0.f}};
#pragma unroll 8
    for (int d = 0; d < 64; ++d) {
      float a[4], b[4];
#pragma unroll
      for (int i = 0; i < 4; ++i) a[i] = khs[(ty*4+i)*65 + d];
#pragma unroll
      for (int j = 0; j < 4; ++j) b[j] = kss[(tx*4+j)*65 + d];
#pragma unroll
      for (int i = 0; i < 4; ++i)
#pragma unroll
        for (int j = 0; j < 4; ++j) acc[i][j] += a[i]*b[j];
    }
#pragma unroll
    for (int i = 0; i < 4; ++i) {
#pragma unroll
      for (int j = 0; j < 4; ++j) {
        int m = m0 + tx*4 + j;
        float s = ksnb[m] - 2.f*acc[i][j];
        if (LTPAIR(s,m, bs[i][3],bm[i][3])) {
          if (LTPAIR(s,m, bs[i][1],bm[i][1])) {
            bs[i][3]=bs[i][2]; bm[i][3]=bm[i][2];
            bs[i][2]=bs[i][1]; bm[i][2]=bm[i][1];
            if (LTPAIR(s,m, bs[i][0],bm[i][0])) { bs[i][1]=bs[i][0]; bm[i][1]=bm[i][0]; bs[i][0]=s; bm[i][0]=m; }
            else { bs[i][1]=s; bm[i][1]=m; }
          } else {
            if (LTPAIR(s,m, bs[i][2],bm[i][2])) { bs[i][3]=bs[i][2]; bm[i][3]=bm[i][2]; bs[i][2]=s; bm[i][2]=m; }
            else { bs[i][3]=s; bm[i][3]=m; }
          }
        }
      }
    }
  }
  __syncthreads();
  // merge 16 partial top-4 lists per row (reuse LDS)
  float* cs = smem;                  // [64][64]
  int*   ci = (int*)(smem + 64*64);  // [64][64]
#pragma unroll
  for (int i = 0; i < 4; ++i)
#pragma unroll
    for (int c = 0; c < 4; ++c) {
      cs[(ty*4+i)*64 + tx*4 + c] = bs[i][c];
      ci[(ty*4+i)*64 + tx*4 + c] = bm[i][c];
    }
  __syncthreads();
  if (tid < 64) {
    float s0=3.4e38f,s1=3.4e38f,s2=3.4e38f,s3=3.4e38f;
    int m0i=0x7fffffff,m1i=0x7fffffff,m2i=0x7fffffff,m3i=0x7fffffff;
    for (int c = 0; c < 64; ++c) {
      float s = cs[tid*64 + c]; int m = ci[tid*64 + c];
      if (LTPAIR(s,m,s3,m3i)) {
        if (LTPAIR(s,m,s1,m1i)) {
          s3=s2;m3i=m2i; s2=s1;m2i=m1i;
          if (LTPAIR(s,m,s0,m0i)) { s1=s0;m1i=m0i; s0=s;m0i=m; } else { s1=s;m1i=m; }
        } else {
          if (LTPAIR(s,m,s2,m2i)) { s3=s2;m3i=m2i; s2=s;m2i=m; } else { s3=s;m3i=m; }
        }
      }
    }
    int* o = idxout + ((size_t)h*TT + n0 + tid)*4;
    o[0]=m0i; o[1]=m1i; o[2]=m2i; o[3]=m3i;
  }
}

// build v_new[h][t][d]
__global__ __launch_bounds__(256) void knn_apply_k(
    const float* __restrict__ qkv, const float* __restrict__ kstore, const float* __restrict__ vstore,
    const int* __restrict__ idx, const int* __restrict__ mask, float* __restrict__ vnew)
{
  const int r = blockIdx.x * 4 + (threadIdx.x >> 6);
  const int lane = threadIdx.x & 63;
  const int h = r >> 11, t = r & (TT-1);
  const float* base = qkv + (size_t)t*C3 + h*DDIM;
  float vh = base[2*CC + lane];
  float* outp = vnew + ((size_t)h*TT + t)*DDIM;
  if (!mask[r]) { outp[lane] = vh; return; }
  float qd = base[lane];
  float kd = base[CC + lane];
  float s0 = waveReduceSum(qd*kd) * 0.125f;
  float sj[4], vj[4];
#pragma unroll
  for (int j = 0; j < 4; ++j) {
    int m = idx[(size_t)r*4 + j];
    const float* kp = kstore + ((size_t)h*MM + m)*DDIM;
    const float* vp = vstore + ((size_t)h*MM + m)*DDIM;
    sj[j] = waveReduceSum(qd * kp[lane]) * 0.125f;
    vj[j] = vp[lane];
  }
  float mx = fmaxf(fmaxf(fmaxf(s0,sj[0]),fmaxf(sj[1],sj[2])),sj[3]);
  float w0 = expf(s0-mx), w1 = expf(sj[0]-mx), w2 = expf(sj[1]-mx), w3 = expf(sj[2]-mx), w4 = expf(sj[3]-mx);
  float Z = w0+w1+w2+w3+w4;
  float vnw = (w0*vh + w1*vj[0] + w2*vj[1] + w3*vj[2] + w4*vj[3]) / Z;
  outp[lane] = 0.5f*vnw + 0.5f*vh;
}

// causal flash attention with v_new; y stored [t][h*64+d]
__global__ __launch_bounds__(256) void attn_k(
    const float* __restrict__ qkv, const float* __restrict__ vnew, float* __restrict__ y)
{
  __shared__ float qs[64*65];
  __shared__ float ksd[64*65];   // keys tile, reused as P tile
  __shared__ float vs[64*65];
  __shared__ float red[64*16];
  __shared__ float rowbc[64];
  const int h = blockIdx.y;
  const int q0 = blockIdx.x * 64;
  const int tid = threadIdx.x;
  const int tx = tid & 15, ty = tid >> 4;
#pragma unroll
  for (int r = 0; r < 16; ++r) {
    int e = tid + r*256;
    int row = e >> 6, d = e & 63;
    qs[row*65 + d] = qkv[(size_t)(q0+row)*C3 + h*DDIM + d];
  }
  float mrow[4], lrow[4], yacc[4][4];
#pragma unroll
  for (int i = 0; i < 4; ++i) {
    mrow[i] = -INFINITY; lrow[i] = 0.f;
#pragma unroll
    for (int j = 0; j < 4; ++j) yacc[i][j] = 0.f;
  }
  const int ntiles = blockIdx.x + 1;
  for (int kt = 0; kt < ntiles; ++kt) {
    __syncthreads();
#pragma unroll
    for (int r = 0; r < 16; ++r) {
      int e = tid + r*256;
      int row = e >> 6, d = e & 63;
      ksd[row*65 + d] = qkv[(size_t)(kt*64+row)*C3 + CC + h*DDIM + d];
      vs[row*65 + d]  = vnew[((size_t)h*TT + kt*64 + row)*DDIM + d];
    }
    __syncthreads();
    float sv[4][4] = {{0.f,0.f,0.f,0.f},{0.f,0.f,0.f,0.f},{0.f,0.f,0.f,0.f},{0.f,0.f,0.f,0.f}};
#pragma unroll 8
    for (int d = 0; d < 64; ++d) {
      float a[4], b[4];
#pragma unroll
      for (int i = 0; i < 4; ++i) a[i] = qs[(ty*4+i)*65 + d];
#pragma unroll
      for (int j = 0; j < 4; ++j) b[j] = ksd[(tx*4+j)*65 + d];
#pragma unroll
      for (int i = 0; i < 4; ++i)
#pragma unroll
        for (int j = 0; j < 4; ++j) sv[i][j] += a[i]*b[j];
    }
    float tmax[4];
#pragma unroll
    for (int i = 0; i < 4; ++i) {
      int row = q0 + ty*4 + i;
      tmax[i] = -INFINITY;
#pragma unroll
      for (int j = 0; j < 4; ++j) {
        int key = kt*64 + tx*4 + j;
        sv[i][j] = (key <= row) ? sv[i][j]*0.125f : -INFINITY;
        tmax[i] = fmaxf(tmax[i], sv[i][j]);
      }
      red[(ty*4+i)*16 + tx] = tmax[i];
    }
    __syncthreads();
    if (tid < 64) {
      float mm = -INFINITY;
#pragma unroll
      for (int c = 0; c < 16; ++c) mm = fmaxf(mm, red[tid*16 + c]);
      rowbc[tid] = mm;
    }
    __syncthreads();
    float scl[4];
#pragma unroll
    for (int i = 0; i < 4; ++i) {
      float nm = fmaxf(mrow[i], rowbc[ty*4+i]);
      scl[i] = expf(mrow[i] - nm);
      mrow[i] = nm;
    }
    // write P into ksd (keys tile no longer needed), update l, rescale y
    float psum[4];
#pragma unroll
    for (int i = 0; i < 4; ++i) {
      psum[i] = 0.f;
#pragma unroll
      for (int j = 0; j < 4; ++j) {
        float p = expf(sv[i][j] - mrow[i]);   // masked -> exp(-inf) = 0
        ksd[(ty*4+i)*65 + tx*4 + j] = p;
        psum[i] += p;
      }
      lrow[i] *= scl[i];
#pragma unroll
      for (int j = 0; j < 4; ++j) yacc[i][j] *= scl[i];
      red[(ty*4+i)*16 + tx] = psum[i];
    }
    __syncthreads();
    if (tid < 64) {
      float ss = 0.f;
#pragma unroll
      for (int c = 0; c < 16; ++c) ss += red[tid*16 + c];
      rowbc[tid] = ss;
    }
    __syncthreads();
#pragma unroll
    for (int i = 0; i < 4; ++i) lrow[i] += rowbc[ty*4+i];
    // PV accumulate
#pragma unroll 8
    for (int kk = 0; kk < 64; ++kk) {
      float a[4], b[4];
#pragma unroll
      for (int i = 0; i < 4; ++i) a[i] = ksd[(ty*4+i)*65 + kk];
#pragma unroll
      for (int j = 0; j < 4; ++j) b[j] = vs[kk*65 + tx*4 + j];
#pragma unroll
      for (int i = 0; i < 4; ++i)
#pragma unroll
        for (int j = 0; j < 4; ++j) yacc[i][j] += a[i]*b[j];
    }
  }
#pragma unroll
  for (int i = 0; i < 4; ++i)
#pragma unroll
    for (int j = 0; j < 4; ++j)
      y[(size_t)(q0 + ty*4 + i)*CC + h*DDIM + tx*4 + j] = yacc[i][j] / lrow[i];
}

extern "C" void kernel_launch(void* const* d_in, const int* in_sizes, int n_in,
                              void* d_out, int out_size, void* d_ws, size_t ws_size,
                              hipStream_t stream) {
  const float* x   = (const float*)d_in[0];
  const float* wat = (const float*)d_in[1];
  const float* wpr = (const float*)d_in[2];
  const float* kst = (const float*)d_in[3];
  const float* vst = (const float*)d_in[4];
  float* out = (float*)d_out;

  float* ws   = (float*)d_ws;
  float* qkv  = ws;                                // TT*C3      = 6291456 floats
  float* vnew = qkv + (size_t)TT*C3;               // HH*TT*DDIM = 2097152
  float* yb   = vnew + (size_t)HH*TT*DDIM;         // TT*CC      = 2097152
  float* ksn  = yb + (size_t)TT*CC;                // HH*MM      = 131072
  int*   idxb = (int*)(ksn + (size_t)HH*MM);       // HH*TT*4    = 131072
  int*   maskb= idxb + (size_t)HH*TT*4;            // HH*TT      = 32768

  // 1. qkv = x @ c_attn_w^T
  gemm_nt_f32<<<dim3(C3/64, TT/64), 256, 0, stream>>>(x, wat, qkv, TT, C3, CC);
  // 2. |key_store|^2 per row
  sqnorm_k<<<dim3((HH*MM)/256), 256, 0, stream>>>(kst, ksn);
  // 3. mask from softmax of last attention row (exact fp32)
  attlast_mask_k<<<dim3(HH), 256, 0, stream>>>(qkv, maskb);
  // 4. top-4 nearest store keys per (h, t)
  knn_topk_k<<<dim3(TT/64, HH), 256, 0, stream>>>(qkv, kst, ksn, idxb);
  // 5. v_new
  knn_apply_k<<<dim3((HH*TT)/4), 256, 0, stream>>>(qkv, kst, vst, idxb, maskb, vnew);
  // 6. causal attention with v_new
  attn_k<<<dim3(TT/64, HH), 256, 0, stream>>>(qkv, vnew, yb);
  // 7. out = y @ c_proj_w^T
  gemm_nt_f32<<<dim3(CC/64, TT/64), 256, 0, stream>>>(yb, wpr, out, TT, CC, CC);
}

// Round 2
// 1087.367 us; speedup vs baseline: 1.6645x; 1.6645x over previous
//
#include <hip/hip_runtime.h>
#include <hip/hip_bf16.h>
#include <math.h>

#define TT 2048
#define CC 1024
#define HH 16
#define DDIM 64
#define MM 8192
#define C3 3072
#define SBIAS 256.0f

#define LTPAIR(sa,ma,sb,mb) ((sa) < (sb) || ((sa) == (sb) && (ma) < (mb)))

typedef __bf16 bf16x8 __attribute__((ext_vector_type(8)));
typedef float f32x4 __attribute__((ext_vector_type(4)));

__device__ __forceinline__ float waveReduceSum(float v) {
#pragma unroll
  for (int off = 32; off > 0; off >>= 1) v += __shfl_xor(v, off, 64);
  return v;
}
__device__ __forceinline__ unsigned waveMinU32(unsigned v) {
#pragma unroll
  for (int off = 32; off > 0; off >>= 1) {
    unsigned o = __shfl_xor(v, off, 64);
    v = (o < v) ? o : v;
  }
  return v;
}
__device__ __forceinline__ unsigned umn(unsigned a, unsigned b){ return a<b?a:b; }
__device__ __forceinline__ unsigned umx(unsigned a, unsigned b){ return a>b?a:b; }

// ---------------- fp32 tiled GEMM (C[i][j] = sum_k A[i][k]*B[j][k]) ----------------
__global__ __launch_bounds__(256) void gemm_nt_f32(
    const float* __restrict__ A, const float* __restrict__ B,
    float* __restrict__ Cmat, int Mr, int Nc, int Kd)
{
  __shared__ float As[32][65];
  __shared__ float Bs[32][65];
  const int tid = threadIdx.x;
  const int tx = tid & 15, ty = tid >> 4;
  const float* Ab = A + (size_t)blockIdx.y * 64 * Kd;
  const float* Bb = B + (size_t)blockIdx.x * 64 * Kd;
  float acc[4][4] = {{0.f,0.f,0.f,0.f},{0.f,0.f,0.f,0.f},{0.f,0.f,0.f,0.f},{0.f,0.f,0.f,0.f}};
  for (int k0 = 0; k0 < Kd; k0 += 32) {
#pragma unroll
    for (int r = 0; r < 8; ++r) {
      int e = tid + r * 256;
      int row = e >> 5, kk = e & 31;
      As[kk][row] = Ab[(size_t)row * Kd + k0 + kk];
      Bs[kk][row] = Bb[(size_t)row * Kd + k0 + kk];
    }
    __syncthreads();
#pragma unroll 8
    for (int kk = 0; kk < 32; ++kk) {
      float a[4], b[4];
#pragma unroll
      for (int i = 0; i < 4; ++i) a[i] = As[kk][ty*4+i];
#pragma unroll
      for (int j = 0; j < 4; ++j) b[j] = Bs[kk][tx*4+j];
#pragma unroll
      for (int i = 0; i < 4; ++i)
#pragma unroll
        for (int j = 0; j < 4; ++j) acc[i][j] += a[i]*b[j];
    }
    __syncthreads();
  }
#pragma unroll
  for (int i = 0; i < 4; ++i)
#pragma unroll
    for (int j = 0; j < 4; ++j)
      Cmat[(size_t)(blockIdx.y*64 + ty*4 + i) * Nc + blockIdx.x*64 + tx*4 + j] = acc[i][j];
}

// ---------------- conversions ----------------
// key_store -> bf16 copy + squared norms (raw + biased)
__global__ __launch_bounds__(256) void conv_ks_k(const float* __restrict__ ks,
    __hip_bfloat16* __restrict__ ksb, float* __restrict__ ksn, float* __restrict__ ksnb)
{
  int row = blockIdx.x*4 + (threadIdx.x>>6);   // HH*MM rows
  int lane = threadIdx.x & 63;
  float v = ks[(size_t)row*64 + lane];
  float sq = waveReduceSum(v*v);
  ksb[(size_t)row*64 + lane] = __float2bfloat16(v);
  if (lane == 0) { ksn[row] = sq; ksnb[row] = sq + SBIAS; }
}

// k (from qkv) -> kb[h][t][d] bf16
__global__ __launch_bounds__(256) void conv_kb_k(const float* __restrict__ qkv,
    __hip_bfloat16* __restrict__ kb)
{
  int e = blockIdx.x*256 + threadIdx.x;        // 262144 groups of 8
  int dg = e & 7; int t = (e>>3) & (TT-1); int h = e >> 14;
  const float* src = qkv + (size_t)t*C3 + CC + h*64 + dg*8;
  __hip_bfloat16* dst = kb + ((size_t)(h*TT + t)*64 + dg*8);
#pragma unroll
  for (int i = 0; i < 8; ++i) dst[i] = __float2bfloat16(src[i]);
}

// ---------------- exact fp32 softmax of last attention row -> mask ----------------
__global__ __launch_bounds__(256) void attlast_mask_k(const float* __restrict__ qkv, int* __restrict__ mask)
{
  const int h = blockIdx.x;
  __shared__ float ql[64];
  __shared__ float lg[TT];
  __shared__ float red[256];
  const int tid = threadIdx.x;
  if (tid < 64) ql[tid] = qkv[(size_t)(TT-1)*C3 + h*DDIM + tid];
  __syncthreads();
  float lmax = -INFINITY;
  for (int t = tid; t < TT; t += 256) {
    const float* kr = qkv + (size_t)t*C3 + CC + h*DDIM;
    float s = 0.f;
#pragma unroll
    for (int d = 0; d < 64; ++d) s += ql[d] * kr[d];
    s *= 0.125f;
    lg[t] = s;
    lmax = fmaxf(lmax, s);
  }
  red[tid] = lmax; __syncthreads();
  for (int off = 128; off > 0; off >>= 1) { if (tid < off) red[tid] = fmaxf(red[tid], red[tid+off]); __syncthreads(); }
  float mx = red[0];
  __syncthreads();
  float ls = 0.f;
  for (int t = tid; t < TT; t += 256) { float e = expf(lg[t]-mx); lg[t] = e; ls += e; }
  red[tid] = ls; __syncthreads();
  for (int off = 128; off > 0; off >>= 1) { if (tid < off) red[tid] += red[tid+off]; __syncthreads(); }
  float Z = red[0];
  for (int t = tid; t < TT; t += 256) mask[h*TT + t] = (lg[t]/Z >= 1.220703125e-4f) ? 1 : 0;
}

// ---------------- phase A: bf16 MFMA scoring + per-cell top-4 chunk-mins ----------------
// grid 512 (XCD-chunk swizzled), 256 thr = 4 waves; block = 64 n-rows of one head, all M.
// chunk = 4 cols {t*64 + b*16 + cr}; packed cand = (scorebits & 0xFFFFFF80) | t
__global__ __launch_bounds__(256) void knn_chunkmin_k(
    const __hip_bfloat16* __restrict__ kb, const __hip_bfloat16* __restrict__ ksb,
    const float* __restrict__ ksnb, unsigned int* __restrict__ cand)
{
  __shared__ __align__(16) char lds[2*8192];
  const int tid = threadIdx.x;
  const int bid = blockIdx.x;
  const int orig = (bid & 7)*64 + (bid >> 3);   // XCD-chunked swizzle (512 = 8*64)
  const int h  = orig >> 5;
  const int n0 = (orig & 31) * 64;
  const int w  = tid >> 6;
  const int l  = tid & 63;
  const int cr = l & 15, hi = l >> 4;

  // A fragments: rows n0 + w*16 + cr, k-groups g
  bf16x8 af0, af1;
  {
    const __hip_bfloat16* kbh = kb + (size_t)h*TT*64 + (size_t)(n0 + w*16 + cr)*64;
    af0 = *reinterpret_cast<const bf16x8*>(kbh + 0*32 + hi*8);
    af1 = *reinterpret_cast<const bf16x8*>(kbh + 1*32 + hi*8);
  }
  const __hip_bfloat16* ksbh = ksb + (size_t)h*MM*64;
  const float* ksnh = ksnb + (size_t)h*MM;

  // staging addresses (thread covers 32B = two 16B chunks of the 8KB tile)
  const int c0 = tid*2, c1 = tid*2 + 1;
  const int wb0 = (c0>>3)*128 + (((c0&7) ^ ((c0>>3)&7))*16);
  const int wb1 = (c1>>3)*128 + (((c1&7) ^ ((c1>>3)&7))*16);
  // frag read base (swizzled): byte = b*2048 + (l&15)*128 + ((g*4+hi)^(l&7))*16
  const int rb0 = (l&15)*128 + (((0 + hi) ^ (l&7))*16);
  const int rb1 = (l&15)*128 + (((4 + hi) ^ (l&7))*16);

  unsigned cnd[4][4];
#pragma unroll
  for (int i = 0; i < 4; ++i)
#pragma unroll
    for (int c = 0; c < 4; ++c) cnd[i][c] = 0xFFFFFFFFu;

  // prologue: stage tile 0
  uint4 r0, r1;
  {
    const uint4* g = reinterpret_cast<const uint4*>(ksbh);
    r0 = g[c0]; r1 = g[c1];
    *reinterpret_cast<uint4*>(lds + wb0) = r0;
    *reinterpret_cast<uint4*>(lds + wb1) = r1;
  }

  for (int tt = 0; tt < 128; ++tt) {
    __syncthreads();
    const int buf = tt & 1;
    char* ldsb = lds + buf*8192;
    if (tt + 1 < 128) {          // issue next-tile global loads early
      const uint4* g = reinterpret_cast<const uint4*>(ksbh + (size_t)(tt+1)*64*64);
      r0 = g[c0]; r1 = g[c1];
    }
    float kn0 = ksnh[tt*64 +  0 + cr];
    float kn1 = ksnh[tt*64 + 16 + cr];
    float kn2 = ksnh[tt*64 + 32 + cr];
    float kn3 = ksnh[tt*64 + 48 + cr];

    f32x4 acc[4];
#pragma unroll
    for (int b = 0; b < 4; ++b) {
      bf16x8 bf0 = *reinterpret_cast<const bf16x8*>(ldsb + b*2048 + rb0);
      bf16x8 bf1 = *reinterpret_cast<const bf16x8*>(ldsb + b*2048 + rb1);
      f32x4 z = {0.f, 0.f, 0.f, 0.f};
      z = __builtin_amdgcn_mfma_f32_16x16x32_bf16(af0, bf0, z, 0, 0, 0);
      z = __builtin_amdgcn_mfma_f32_16x16x32_bf16(af1, bf1, z, 0, 0, 0);
      acc[b] = z;
    }
#pragma unroll
    for (int i = 0; i < 4; ++i) {
      float s0 = fmaf(acc[0][i], -2.f, kn0);
      float s1 = fmaf(acc[1][i], -2.f, kn1);
      float s2 = fmaf(acc[2][i], -2.f, kn2);
      float s3 = fmaf(acc[3][i], -2.f, kn3);
      float m4 = fminf(fminf(s0, s1), fminf(s2, s3));
      unsigned x = (__float_as_uint(m4) & 0xFFFFFF80u) | (unsigned)tt;
      unsigned tmp;
      tmp = umn(cnd[i][0], x); x = umx(cnd[i][0], x); cnd[i][0] = tmp;
      tmp = umn(cnd[i][1], x); x = umx(cnd[i][1], x); cnd[i][1] = tmp;
      tmp = umn(cnd[i][2], x); x = umx(cnd[i][2], x); cnd[i][2] = tmp;
      cnd[i][3] = umn(cnd[i][3], x);
    }
    if (tt + 1 < 128) {          // write next tile into the other buffer
      char* ldsn = lds + (buf^1)*8192;
      *reinterpret_cast<uint4*>(ldsn + wb0) = r0;
      *reinterpret_cast<uint4*>(ldsn + wb1) = r1;
    }
  }

#pragma unroll
  for (int i = 0; i < 4; ++i) {
    int n = n0 + w*16 + hi*4 + i;
    reinterpret_cast<uint4*>(cand)[(size_t)(h*TT + n)*16 + cr] =
        make_uint4(cnd[i][0], cnd[i][1], cnd[i][2], cnd[i][3]);
  }
}

// ---------------- phase B: top-8 chunks -> exact fp32 rescore -> top-4 ----------------
__global__ __launch_bounds__(256) void knn_select_k(
    const unsigned int* __restrict__ cand, const float* __restrict__ qkv,
    const float* __restrict__ kstore, const float* __restrict__ ksn,
    int* __restrict__ idxout)
{
  const int row = blockIdx.x*4 + (threadIdx.x>>6);   // HH*TT rows
  const int l = threadIdx.x & 63;
  const int h = row >> 11, t = row & (TT-1);
  unsigned v = cand[(size_t)row*64 + (l&15)*4 + (l>>4)];
  const float kreg = qkv[(size_t)t*C3 + CC + h*64 + l];
  const float* ksh = kstore + (size_t)h*MM*64;
  const float* ksnh = ksn + (size_t)h*MM;

  float bs0=3.4e38f, bs1=3.4e38f, bs2=3.4e38f, bs3=3.4e38f;
  int bm0=0x7fffffff, bm1=0x7fffffff, bm2=0x7fffffff, bm3=0x7fffffff;

  for (int it = 0; it < 8; ++it) {
    unsigned mv = waveMinU32(v);
    if (mv == 0xFFFFFFFFu) break;
    unsigned long long ball = __ballot(v == mv);
    int src = __ffsll(ball) - 1;
    int tIdx = (int)(mv & 127u);
    int crw = src & 15;
    if (l == src) v = 0xFFFFFFFFu;
#pragma unroll
    for (int b = 0; b < 4; ++b) {
      int m = tIdx*64 + b*16 + crw;
      float ksv = ksh[(size_t)m*64 + l];
      float dot = waveReduceSum(kreg * ksv);
      float s = ksnh[m] - 2.f*dot;
      if (LTPAIR(s,m, bs3,bm3)) {
        if (LTPAIR(s,m, bs1,bm1)) {
          bs3=bs2; bm3=bm2; bs2=bs1; bm2=bm1;
          if (LTPAIR(s,m, bs0,bm0)) { bs1=bs0; bm1=bm0; bs0=s; bm0=m; }
          else { bs1=s; bm1=m; }
        } else {
          if (LTPAIR(s,m, bs2,bm2)) { bs3=bs2; bm3=bm2; bs2=s; bm2=m; }
          else { bs3=s; bm3=m; }
        }
      }
    }
  }
  if (l == 0) {
    int* o = idxout + (size_t)row*4;
    o[0]=bm0; o[1]=bm1; o[2]=bm2; o[3]=bm3;
  }
}

// ---------------- build v_new ----------------
__global__ __launch_bounds__(256) void knn_apply_k(
    const float* __restrict__ qkv, const float* __restrict__ kstore, const float* __restrict__ vstore,
    const int* __restrict__ idx, const int* __restrict__ mask, float* __restrict__ vnew)
{
  const int r = blockIdx.x * 4 + (threadIdx.x >> 6);
  const int lane = threadIdx.x & 63;
  const int h = r >> 11, t = r & (TT-1);
  const float* base = qkv + (size_t)t*C3 + h*DDIM;
  float vh = base[2*CC + lane];
  float* outp = vnew + ((size_t)h*TT + t)*DDIM;
  if (!mask[r]) { outp[lane] = vh; return; }
  float qd = base[lane];
  float kd = base[CC + lane];
  float s0 = waveReduceSum(qd*kd) * 0.125f;
  float sj[4], vj[4];
#pragma unroll
  for (int j = 0; j < 4; ++j) {
    int m = idx[(size_t)r*4 + j];
    const float* kp = kstore + ((size_t)h*MM + m)*DDIM;
    const float* vp = vstore + ((size_t)h*MM + m)*DDIM;
    sj[j] = waveReduceSum(qd * kp[lane]) * 0.125f;
    vj[j] = vp[lane];
  }
  float mx = fmaxf(fmaxf(fmaxf(s0,sj[0]),fmaxf(sj[1],sj[2])),sj[3]);
  float w0 = expf(s0-mx), w1 = expf(sj[0]-mx), w2 = expf(sj[1]-mx), w3 = expf(sj[2]-mx), w4 = expf(sj[3]-mx);
  float Z = w0+w1+w2+w3+w4;
  float vnw = (w0*vh + w1*vj[0] + w2*vj[1] + w3*vj[2] + w4*vj[3]) / Z;
  outp[lane] = 0.5f*vnw + 0.5f*vh;
}

// ---------------- causal flash attention with v_new ----------------
__global__ __launch_bounds__(256) void attn_k(
    const float* __restrict__ qkv, const float* __restrict__ vnew, float* __restrict__ y)
{
  __shared__ float qs[64*65];
  __shared__ float ksd[64*65];
  __shared__ float vs[64*65];
  __shared__ float red[64*16];
  __shared__ float rowbc[64];
  const int h = blockIdx.y;
  const int q0 = blockIdx.x * 64;
  const int tid = threadIdx.x;
  const int tx = tid & 15, ty = tid >> 4;
#pragma unroll
  for (int r = 0; r < 16; ++r) {
    int e = tid + r*256;
    int row = e >> 6, d = e & 63;
    qs[row*65 + d] = qkv[(size_t)(q0+row)*C3 + h*DDIM + d];
  }
  float mrow[4], lrow[4], yacc[4][4];
#pragma unroll
  for (int i = 0; i < 4; ++i) {
    mrow[i] = -INFINITY; lrow[i] = 0.f;
#pragma unroll
    for (int j = 0; j < 4; ++j) yacc[i][j] = 0.f;
  }
  const int ntiles = blockIdx.x + 1;
  for (int kt = 0; kt < ntiles; ++kt) {
    __syncthreads();
#pragma unroll
    for (int r = 0; r < 16; ++r) {
      int e = tid + r*256;
      int row = e >> 6, d = e & 63;
      ksd[row*65 + d] = qkv[(size_t)(kt*64+row)*C3 + CC + h*DDIM + d];
      vs[row*65 + d]  = vnew[((size_t)h*TT + kt*64 + row)*DDIM + d];
    }
    __syncthreads();
    float sv[4][4] = {{0.f,0.f,0.f,0.f},{0.f,0.f,0.f,0.f},{0.f,0.f,0.f,0.f},{0.f,0.f,0.f,0.f}};
#pragma unroll 8
    for (int d = 0; d < 64; ++d) {
      float a[4], b[4];
#pragma unroll
      for (int i = 0; i < 4; ++i) a[i] = qs[(ty*4+i)*65 + d];
#pragma unroll
      for (int j = 0; j < 4; ++j) b[j] = ksd[(tx*4+j)*65 + d];
#pragma unroll
      for (int i = 0; i < 4; ++i)
#pragma unroll
        for (int j = 0; j < 4; ++j) sv[i][j] += a[i]*b[j];
    }
    float tmax[4];
#pragma unroll
    for (int i = 0; i < 4; ++i) {
      int rowq = q0 + ty*4 + i;
      tmax[i] = -INFINITY;
#pragma unroll
      for (int j = 0; j < 4; ++j) {
        int key = kt*64 + tx*4 + j;
        sv[i][j] = (key <= rowq) ? sv[i][j]*0.125f : -INFINITY;
        tmax[i] = fmaxf(tmax[i], sv[i][j]);
      }
      red[(ty*4+i)*16 + tx] = tmax[i];
    }
    __syncthreads();
    if (tid < 64) {
      float mm = -INFINITY;
#pragma unroll
      for (int c = 0; c < 16; ++c) mm = fmaxf(mm, red[tid*16 + c]);
      rowbc[tid] = mm;
    }
    __syncthreads();
    float scl[4];
#pragma unroll
    for (int i = 0; i < 4; ++i) {
      float nm = fmaxf(mrow[i], rowbc[ty*4+i]);
      scl[i] = expf(mrow[i] - nm);
      mrow[i] = nm;
    }
    float psum[4];
#pragma unroll
    for (int i = 0; i < 4; ++i) {
      psum[i] = 0.f;
#pragma unroll
      for (int j = 0; j < 4; ++j) {
        float p = expf(sv[i][j] - mrow[i]);
        ksd[(ty*4+i)*65 + tx*4 + j] = p;
        psum[i] += p;
      }
      lrow[i] *= scl[i];
#pragma unroll
      for (int j = 0; j < 4; ++j) yacc[i][j] *= scl[i];
      red[(ty*4+i)*16 + tx] = psum[i];
    }
    __syncthreads();
    if (tid < 64) {
      float ss = 0.f;
#pragma unroll
      for (int c = 0; c < 16; ++c) ss += red[tid*16 + c];
      rowbc[tid] = ss;
    }
    __syncthreads();
#pragma unroll
    for (int i = 0; i < 4; ++i) lrow[i] += rowbc[ty*4+i];
#pragma unroll 8
    for (int kk = 0; kk < 64; ++kk) {
      float a[4], b[4];
#pragma unroll
      for (int i = 0; i < 4; ++i) a[i] = ksd[(ty*4+i)*65 + kk];
#pragma unroll
      for (int j = 0; j < 4; ++j) b[j] = vs[kk*65 + tx*4 + j];
#pragma unroll
      for (int i = 0; i < 4; ++i)
#pragma unroll
        for (int j = 0; j < 4; ++j) yacc[i][j] += a[i]*b[j];
    }
  }
#pragma unroll
  for (int i = 0; i < 4; ++i)
#pragma unroll
    for (int j = 0; j < 4; ++j)
      y[(size_t)(q0 + ty*4 + i)*CC + h*DDIM + tx*4 + j] = yacc[i][j] / lrow[i];
}

extern "C" void kernel_launch(void* const* d_in, const int* in_sizes, int n_in,
                              void* d_out, int out_size, void* d_ws, size_t ws_size,
                              hipStream_t stream) {
  const float* x   = (const float*)d_in[0];
  const float* wat = (const float*)d_in[1];
  const float* wpr = (const float*)d_in[2];
  const float* kst = (const float*)d_in[3];
  const float* vst = (const float*)d_in[4];
  float* out = (float*)d_out;

  // workspace layout (float units), with aliasing:
  //   qkv 6291456 | ksn 131072 | ksnb 131072 | idx 131072 | mask 32768
  //   kb (bf16, 1048576 f-slots) | ksbRegion 4194304 (ksb bf16; later yb 2097152)
  //   candRegion 2097152 (cand u32; later vnew 2097152)
  float* ws   = (float*)d_ws;
  float* qkv  = ws;
  float* ksn  = qkv + (size_t)TT*C3;
  float* ksnb = ksn + (size_t)HH*MM;
  int*   idxb = (int*)(ksnb + (size_t)HH*MM);
  int*   maskb= idxb + (size_t)HH*TT*4;
  __hip_bfloat16* kb  = (__hip_bfloat16*)(maskb + (size_t)HH*TT);
  float* ksbRegion = (float*)kb + (size_t)HH*TT*DDIM/2;        // 1048576 f-slots for kb
  __hip_bfloat16* ksb = (__hip_bfloat16*)ksbRegion;            // 4194304 f-slots
  float* yb = ksbRegion;                                        // alias (after phase A)
  float* candRegion = ksbRegion + (size_t)HH*MM*DDIM/2;
  unsigned int* candb = (unsigned int*)candRegion;              // 2097152 u32
  float* vnew = candRegion;                                     // alias (after select)

  // 1. qkv = x @ c_attn_w^T  (fp32 exact: feeds mask + rescore)
  gemm_nt_f32<<<dim3(C3/64, TT/64), 256, 0, stream>>>(x, wat, qkv, TT, C3, CC);
  // 2. key_store -> bf16 + norms
  conv_ks_k<<<dim3(HH*MM/4), 256, 0, stream>>>(kst, ksb, ksn, ksnb);
  // 3. k -> bf16
  conv_kb_k<<<dim3(HH*TT*DDIM/8/256), 256, 0, stream>>>(qkv, kb);
  // 4. mask (exact fp32)
  attlast_mask_k<<<dim3(HH), 256, 0, stream>>>(qkv, maskb);
  // 5. phase A: MFMA chunk-min scoring
  knn_chunkmin_k<<<dim3(512), 256, 0, stream>>>(kb, ksb, ksnb, candb);
  // 6. phase B: exact rescore -> top-4 indices
  knn_select_k<<<dim3(HH*TT/4), 256, 0, stream>>>(candb, qkv, kst, ksn, idxb);
  // 7. v_new  (vnew aliases candb region - select already consumed it)
  knn_apply_k<<<dim3(HH*TT/4), 256, 0, stream>>>(qkv, kst, vst, idxb, maskb, vnew);
  // 8. causal attention (yb aliases ksb region - phase A already consumed it)
  attn_k<<<dim3(TT/64, HH), 256, 0, stream>>>(qkv, vnew, yb);
  // 9. out = y @ c_proj_w^T
  gemm_nt_f32<<<dim3(CC/64, TT/64), 256, 0, stream>>>(yb, wpr, out, TT, CC, CC);
}

// Round 3
// 535.927 us; speedup vs baseline: 3.3772x; 2.0289x over previous
//
#include <hip/hip_runtime.h>
#include <hip/hip_bf16.h>
#include <math.h>

#define TT 2048
#define CC 1024
#define HH 16
#define DDIM 64
#define MM 8192
#define C3 3072
#define SBIAS 256.0f

#define LTPAIR(sa,ma,sb,mb) ((sa) < (sb) || ((sa) == (sb) && (ma) < (mb)))

typedef __bf16 bf16x8 __attribute__((ext_vector_type(8)));
typedef float f32x4 __attribute__((ext_vector_type(4)));

__device__ __forceinline__ float waveReduceSum(float v) {
#pragma unroll
  for (int off = 32; off > 0; off >>= 1) v += __shfl_xor(v, off, 64);
  return v;
}
__device__ __forceinline__ unsigned waveMinU32(unsigned v) {
#pragma unroll
  for (int off = 32; off > 0; off >>= 1) {
    unsigned o = __shfl_xor(v, off, 64);
    v = (o < v) ? o : v;
  }
  return v;
}
__device__ __forceinline__ unsigned umn(unsigned a, unsigned b){ return a<b?a:b; }
__device__ __forceinline__ unsigned umx(unsigned a, unsigned b){ return a>b?a:b; }

// ---------------- conversions ----------------
// fp32 -> bf16 hi + lo (exact n8*8 elements, n8 = multiple of 256 per grid)
__global__ __launch_bounds__(256) void conv_split_k(const float* __restrict__ src,
    __hip_bfloat16* __restrict__ hi, __hip_bfloat16* __restrict__ lo)
{
  size_t i = (size_t)blockIdx.x*256 + threadIdx.x;
  const float4* p = (const float4*)(src + i*8);
  float4 a = p[0], b = p[1];
  float v[8] = {a.x,a.y,a.z,a.w,b.x,b.y,b.z,b.w};
  bf16x8 H, L;
#pragma unroll
  for (int e = 0; e < 8; ++e) {
    __bf16 hb = (__bf16)v[e];
    H[e] = hb;
    L[e] = (__bf16)(v[e] - (float)hb);
  }
  *reinterpret_cast<bf16x8*>(hi + i*8) = H;
  *reinterpret_cast<bf16x8*>(lo + i*8) = L;
}

// fp32 -> bf16 plain
__global__ __launch_bounds__(256) void conv_bf16_k(const float* __restrict__ src,
    __hip_bfloat16* __restrict__ dst)
{
  size_t i = (size_t)blockIdx.x*256 + threadIdx.x;
  const float4* p = (const float4*)(src + i*8);
  float4 a = p[0], b = p[1];
  float v[8] = {a.x,a.y,a.z,a.w,b.x,b.y,b.z,b.w};
  bf16x8 H;
#pragma unroll
  for (int e = 0; e < 8; ++e) H[e] = (__bf16)v[e];
  *reinterpret_cast<bf16x8*>(dst + i*8) = H;
}

// key_store -> bf16 copy + squared norms (raw + biased)
__global__ __launch_bounds__(256) void conv_ks_k(const float* __restrict__ ks,
    __hip_bfloat16* __restrict__ ksb, float* __restrict__ ksn, float* __restrict__ ksnb)
{
  int row = blockIdx.x*4 + (threadIdx.x>>6);   // HH*MM rows
  int lane = threadIdx.x & 63;
  float v = ks[(size_t)row*64 + lane];
  float sq = waveReduceSum(v*v);
  ksb[(size_t)row*64 + lane] = __float2bfloat16(v);
  if (lane == 0) { ksn[row] = sq; ksnb[row] = sq + SBIAS; }
}

// k (from qkv) -> kb[h][t][d] bf16
__global__ __launch_bounds__(256) void conv_kb_k(const float* __restrict__ qkv,
    __hip_bfloat16* __restrict__ kb)
{
  int e = blockIdx.x*256 + threadIdx.x;        // 262144 groups of 8
  int dg = e & 7; int t = (e>>3) & (TT-1); int h = e >> 14;
  const float* src = qkv + (size_t)t*C3 + CC + h*64 + dg*8;
  __hip_bfloat16* dst = kb + ((size_t)(h*TT + t)*64 + dg*8);
#pragma unroll
  for (int i = 0; i < 8; ++i) dst[i] = __float2bfloat16(src[i]);
}

// vnew [h][t][dv] fp32 -> vbT [h][dv][t] bf16
__global__ __launch_bounds__(256) void vtrans_k(const float* __restrict__ vnew,
    __hip_bfloat16* __restrict__ vbT)
{
  __shared__ float tbuf[64][65];
  const int h = blockIdx.y, t0 = blockIdx.x*64, tid = threadIdx.x;
#pragma unroll
  for (int r = 0; r < 16; ++r) {
    int e = r*256 + tid; int row = e>>6, dv = e&63;
    tbuf[row][dv] = vnew[((size_t)h*TT + t0 + row)*64 + dv];
  }
  __syncthreads();
#pragma unroll
  for (int r = 0; r < 16; ++r) {
    int e = r*256 + tid; int dv = e>>6, tt = e&63;
    vbT[((size_t)h*64 + dv)*TT + t0 + tt] = __float2bfloat16(tbuf[tt][dv]);
  }
}

// ---------------- MFMA GEMM: C[m][n] = sum_k A[m][k]*B[n][k] ----------------
// SPLIT: A,B given as bf16 hi/lo pairs, 3-product bf16x3 accumulation (fp32-ish).
// 128x128 tile, BK=32 (SPLIT, [hi32|lo32] in LDS row) or BK=64 (plain).
template<bool SPLIT>
__global__ __launch_bounds__(256) void gemm_mfma_k(
    const __hip_bfloat16* __restrict__ Ah, const __hip_bfloat16* __restrict__ Al,
    const __hip_bfloat16* __restrict__ Bh, const __hip_bfloat16* __restrict__ Bl,
    float* __restrict__ Cc, int M, int N, int K)
{
  __shared__ __align__(16) char lds[32768];   // A [128][128B] | B [128][128B]
  const int tid = threadIdx.x;
  const int nbx = N >> 7;
  const int by = blockIdx.x / nbx, bx = blockIdx.x - by*nbx;
  const int m0 = by << 7, n0 = bx << 7;
  const int w = tid >> 6;
  const int l = tid & 63;
  const int wi = w >> 1, wj = w & 1;
  const int fr = l & 15, fo = l >> 4;
  const int kw = SPLIT ? 32 : 64;
  const int nsteps = K / kw;

  f32x4 acc[4][4];
#pragma unroll
  for (int i = 0; i < 4; ++i)
#pragma unroll
    for (int j = 0; j < 4; ++j) acc[i][j] = f32x4{0.f,0.f,0.f,0.f};

  int srow[4], schg[4];
#pragma unroll
  for (int r = 0; r < 4; ++r) {
    int s = r*256 + tid;
    srow[r] = s >> 3;
    schg[r] = (s & 7) ^ (srow[r] & 7);
  }

  for (int st = 0; st < nsteps; ++st) {
    const int k0 = st * kw;
    uint4 ra[4], rb[4];
#pragma unroll
    for (int r = 0; r < 4; ++r) {
      const __hip_bfloat16 *pa, *pb;
      if (SPLIT) {
        pa = (schg[r] < 4 ? Ah : Al) + (size_t)(m0+srow[r])*K + k0 + (schg[r]&3)*8;
        pb = (schg[r] < 4 ? Bh : Bl) + (size_t)(n0+srow[r])*K + k0 + (schg[r]&3)*8;
      } else {
        pa = Ah + (size_t)(m0+srow[r])*K + k0 + schg[r]*8;
        pb = Bh + (size_t)(n0+srow[r])*K + k0 + schg[r]*8;
      }
      ra[r] = *(const uint4*)pa;
      rb[r] = *(const uint4*)pb;
    }
    __syncthreads();
#pragma unroll
    for (int r = 0; r < 4; ++r) {
      int s = r*256 + tid;
      *(uint4*)(lds + s*16) = ra[r];
      *(uint4*)(lds + 16384 + s*16) = rb[r];
    }
    __syncthreads();

    if (SPLIT) {
      bf16x8 bhf[4], blf[4];
#pragma unroll
      for (int j = 0; j < 4; ++j) {
        int row = wj*64 + j*16 + fr;
        bhf[j] = *(const bf16x8*)(lds + 16384 + row*128 + ((fo     ^ (row&7))*16));
        blf[j] = *(const bf16x8*)(lds + 16384 + row*128 + (((4+fo) ^ (row&7))*16));
      }
#pragma unroll
      for (int i = 0; i < 4; ++i) {
        int row = wi*64 + i*16 + fr;
        bf16x8 ah = *(const bf16x8*)(lds + row*128 + ((fo     ^ (row&7))*16));
        bf16x8 al = *(const bf16x8*)(lds + row*128 + (((4+fo) ^ (row&7))*16));
#pragma unroll
        for (int j = 0; j < 4; ++j) {
          acc[i][j] = __builtin_amdgcn_mfma_f32_16x16x32_bf16(al, bhf[j], acc[i][j], 0,0,0);
          acc[i][j] = __builtin_amdgcn_mfma_f32_16x16x32_bf16(ah, blf[j], acc[i][j], 0,0,0);
          acc[i][j] = __builtin_amdgcn_mfma_f32_16x16x32_bf16(ah, bhf[j], acc[i][j], 0,0,0);
        }
      }
    } else {
#pragma unroll
      for (int kk = 0; kk < 2; ++kk) {
        bf16x8 bf[4];
#pragma unroll
        for (int j = 0; j < 4; ++j) {
          int row = wj*64 + j*16 + fr;
          bf[j] = *(const bf16x8*)(lds + 16384 + row*128 + (((kk*4+fo) ^ (row&7))*16));
        }
#pragma unroll
        for (int i = 0; i < 4; ++i) {
          int row = wi*64 + i*16 + fr;
          bf16x8 af = *(const bf16x8*)(lds + row*128 + (((kk*4+fo) ^ (row&7))*16));
#pragma unroll
          for (int j = 0; j < 4; ++j)
            acc[i][j] = __builtin_amdgcn_mfma_f32_16x16x32_bf16(af, bf[j], acc[i][j], 0,0,0);
        }
      }
    }
  }

#pragma unroll
  for (int i = 0; i < 4; ++i) {
    int mr = m0 + wi*64 + i*16 + fo*4;
#pragma unroll
    for (int j = 0; j < 4; ++j) {
      int nc = n0 + wj*64 + j*16 + fr;
#pragma unroll
      for (int e = 0; e < 4; ++e)
        Cc[(size_t)(mr+e)*N + nc] = acc[i][j][e];
    }
  }
}

// ---------------- exact fp32 softmax of last attention row -> mask ----------------
__global__ __launch_bounds__(256) void attlast_mask_k(const float* __restrict__ qkv, int* __restrict__ mask)
{
  const int h = blockIdx.x;
  __shared__ float ql[64];
  __shared__ float lg[TT];
  __shared__ float red[256];
  const int tid = threadIdx.x;
  if (tid < 64) ql[tid] = qkv[(size_t)(TT-1)*C3 + h*DDIM + tid];
  __syncthreads();
  float lmax = -INFINITY;
  for (int t = tid; t < TT; t += 256) {
    const float* kr = qkv + (size_t)t*C3 + CC + h*DDIM;
    float s = 0.f;
#pragma unroll
    for (int d = 0; d < 64; ++d) s += ql[d] * kr[d];
    s *= 0.125f;
    lg[t] = s;
    lmax = fmaxf(lmax, s);
  }
  red[tid] = lmax; __syncthreads();
  for (int off = 128; off > 0; off >>= 1) { if (tid < off) red[tid] = fmaxf(red[tid], red[tid+off]); __syncthreads(); }
  float mx = red[0];
  __syncthreads();
  float ls = 0.f;
  for (int t = tid; t < TT; t += 256) { float e = expf(lg[t]-mx); lg[t] = e; ls += e; }
  red[tid] = ls; __syncthreads();
  for (int off = 128; off > 0; off >>= 1) { if (tid < off) red[tid] += red[tid+off]; __syncthreads(); }
  float Z = red[0];
  for (int t = tid; t < TT; t += 256) mask[h*TT + t] = (lg[t]/Z >= 1.220703125e-4f) ? 1 : 0;
}

// ---------------- phase A: bf16 MFMA scoring + per-cell top-4 chunk-mins ----------------
__global__ __launch_bounds__(256) void knn_chunkmin_k(
    const __hip_bfloat16* __restrict__ kb, const __hip_bfloat16* __restrict__ ksb,
    const float* __restrict__ ksnb, unsigned int* __restrict__ cand)
{
  __shared__ __align__(16) char lds[2*8192];
  const int tid = threadIdx.x;
  const int bid = blockIdx.x;
  const int orig = (bid & 7)*64 + (bid >> 3);
  const int h  = orig >> 5;
  const int n0 = (orig & 31) * 64;
  const int w  = tid >> 6;
  const int l  = tid & 63;
  const int cr = l & 15, hi = l >> 4;

  bf16x8 af0, af1;
  {
    const __hip_bfloat16* kbh = kb + (size_t)h*TT*64 + (size_t)(n0 + w*16 + cr)*64;
    af0 = *reinterpret_cast<const bf16x8*>(kbh + 0*32 + hi*8);
    af1 = *reinterpret_cast<const bf16x8*>(kbh + 1*32 + hi*8);
  }
  const __hip_bfloat16* ksbh = ksb + (size_t)h*MM*64;
  const float* ksnh = ksnb + (size_t)h*MM;

  const int c0 = tid*2, c1 = tid*2 + 1;
  const int wb0 = (c0>>3)*128 + (((c0&7) ^ ((c0>>3)&7))*16);
  const int wb1 = (c1>>3)*128 + (((c1&7) ^ ((c1>>3)&7))*16);
  const int rb0 = (l&15)*128 + (((0 + hi) ^ (l&7))*16);
  const int rb1 = (l&15)*128 + (((4 + hi) ^ (l&7))*16);

  unsigned cnd[4][4];
#pragma unroll
  for (int i = 0; i < 4; ++i)
#pragma unroll
    for (int c = 0; c < 4; ++c) cnd[i][c] = 0xFFFFFFFFu;

  uint4 r0, r1;
  {
    const uint4* g = reinterpret_cast<const uint4*>(ksbh);
    r0 = g[c0]; r1 = g[c1];
    *reinterpret_cast<uint4*>(lds + wb0) = r0;
    *reinterpret_cast<uint4*>(lds + wb1) = r1;
  }

  for (int tt = 0; tt < 128; ++tt) {
    __syncthreads();
    const int buf = tt & 1;
    char* ldsb = lds + buf*8192;
    if (tt + 1 < 128) {
      const uint4* g = reinterpret_cast<const uint4*>(ksbh + (size_t)(tt+1)*64*64);
      r0 = g[c0]; r1 = g[c1];
    }
    float kn0 = ksnh[tt*64 +  0 + cr];
    float kn1 = ksnh[tt*64 + 16 + cr];
    float kn2 = ksnh[tt*64 + 32 + cr];
    float kn3 = ksnh[tt*64 + 48 + cr];

    f32x4 acc[4];
#pragma unroll
    for (int b = 0; b < 4; ++b) {
      bf16x8 bf0 = *reinterpret_cast<const bf16x8*>(ldsb + b*2048 + rb0);
      bf16x8 bf1 = *reinterpret_cast<const bf16x8*>(ldsb + b*2048 + rb1);
      f32x4 z = {0.f, 0.f, 0.f, 0.f};
      z = __builtin_amdgcn_mfma_f32_16x16x32_bf16(af0, bf0, z, 0, 0, 0);
      z = __builtin_amdgcn_mfma_f32_16x16x32_bf16(af1, bf1, z, 0, 0, 0);
      acc[b] = z;
    }
#pragma unroll
    for (int i = 0; i < 4; ++i) {
      float s0 = fmaf(acc[0][i], -2.f, kn0);
      float s1 = fmaf(acc[1][i], -2.f, kn1);
      float s2 = fmaf(acc[2][i], -2.f, kn2);
      float s3 = fmaf(acc[3][i], -2.f, kn3);
      float m4 = fminf(fminf(s0, s1), fminf(s2, s3));
      unsigned x = (__float_as_uint(m4) & 0xFFFFFF80u) | (unsigned)tt;
      unsigned tmp;
      tmp = umn(cnd[i][0], x); x = umx(cnd[i][0], x); cnd[i][0] = tmp;
      tmp = umn(cnd[i][1], x); x = umx(cnd[i][1], x); cnd[i][1] = tmp;
      tmp = umn(cnd[i][2], x); x = umx(cnd[i][2], x); cnd[i][2] = tmp;
      cnd[i][3] = umn(cnd[i][3], x);
    }
    if (tt + 1 < 128) {
      char* ldsn = lds + (buf^1)*8192;
      *reinterpret_cast<uint4*>(ldsn + wb0) = r0;
      *reinterpret_cast<uint4*>(ldsn + wb1) = r1;
    }
  }

#pragma unroll
  for (int i = 0; i < 4; ++i) {
    int n = n0 + w*16 + hi*4 + i;
    reinterpret_cast<uint4*>(cand)[(size_t)(h*TT + n)*16 + cr] =
        make_uint4(cnd[i][0], cnd[i][1], cnd[i][2], cnd[i][3]);
  }
}

// ---------------- phase B: top-8 chunks -> exact fp32 rescore -> top-4 ----------------
__global__ __launch_bounds__(256) void knn_select_k(
    const unsigned int* __restrict__ cand, const float* __restrict__ qkv,
    const float* __restrict__ kstore, const float* __restrict__ ksn,
    int* __restrict__ idxout)
{
  const int row = blockIdx.x*4 + (threadIdx.x>>6);
  const int l = threadIdx.x & 63;
  const int h = row >> 11, t = row & (TT-1);
  unsigned v = cand[(size_t)row*64 + (l&15)*4 + (l>>4)];
  const float kreg = qkv[(size_t)t*C3 + CC + h*64 + l];
  const float* ksh = kstore + (size_t)h*MM*64;
  const float* ksnh = ksn + (size_t)h*MM;

  float bs0=3.4e38f, bs1=3.4e38f, bs2=3.4e38f, bs3=3.4e38f;
  int bm0=0x7fffffff, bm1=0x7fffffff, bm2=0x7fffffff, bm3=0x7fffffff;

  for (int it = 0; it < 8; ++it) {
    unsigned mv = waveMinU32(v);
    if (mv == 0xFFFFFFFFu) break;
    unsigned long long ball = __ballot(v == mv);
    int src = __ffsll(ball) - 1;
    int tIdx = (int)(mv & 127u);
    int crw = src & 15;
    if (l == src) v = 0xFFFFFFFFu;
#pragma unroll
    for (int b = 0; b < 4; ++b) {
      int m = tIdx*64 + b*16 + crw;
      float ksv = ksh[(size_t)m*64 + l];
      float dot = waveReduceSum(kreg * ksv);
      float s = ksnh[m] - 2.f*dot;
      if (LTPAIR(s,m, bs3,bm3)) {
        if (LTPAIR(s,m, bs1,bm1)) {
          bs3=bs2; bm3=bm2; bs2=bs1; bm2=bm1;
          if (LTPAIR(s,m, bs0,bm0)) { bs1=bs0; bm1=bm0; bs0=s; bm0=m; }
          else { bs1=s; bm1=m; }
        } else {
          if (LTPAIR(s,m, bs2,bm2)) { bs3=bs2; bm3=bm2; bs2=s; bm2=m; }
          else { bs3=s; bm3=m; }
        }
      }
    }
  }
  if (l == 0) {
    int* o = idxout + (size_t)row*4;
    o[0]=bm0; o[1]=bm1; o[2]=bm2; o[3]=bm3;
  }
}

// ---------------- build v_new ----------------
__global__ __launch_bounds__(256) void knn_apply_k(
    const float* __restrict__ qkv, const float* __restrict__ kstore, const float* __restrict__ vstore,
    const int* __restrict__ idx, const int* __restrict__ mask, float* __restrict__ vnew)
{
  const int r = blockIdx.x * 4 + (threadIdx.x >> 6);
  const int lane = threadIdx.x & 63;
  const int h = r >> 11, t = r & (TT-1);
  const float* base = qkv + (size_t)t*C3 + h*DDIM;
  float vh = base[2*CC + lane];
  float* outp = vnew + ((size_t)h*TT + t)*DDIM;
  if (!mask[r]) { outp[lane] = vh; return; }
  float qd = base[lane];
  float kd = base[CC + lane];
  float s0 = waveReduceSum(qd*kd) * 0.125f;
  float sj[4], vj[4];
#pragma unroll
  for (int j = 0; j < 4; ++j) {
    int m = idx[(size_t)r*4 + j];
    const float* kp = kstore + ((size_t)h*MM + m)*DDIM;
    const float* vp = vstore + ((size_t)h*MM + m)*DDIM;
    sj[j] = waveReduceSum(qd * kp[lane]) * 0.125f;
    vj[j] = vp[lane];
  }
  float mx = fmaxf(fmaxf(fmaxf(s0,sj[0]),fmaxf(sj[1],sj[2])),sj[3]);
  float w0 = expf(s0-mx), w1 = expf(sj[0]-mx), w2 = expf(sj[1]-mx), w3 = expf(sj[2]-mx), w4 = expf(sj[3]-mx);
  float Z = w0+w1+w2+w3+w4;
  float vnw = (w0*vh + w1*vj[0] + w2*vj[1] + w3*vj[2] + w4*vj[3]) / Z;
  outp[lane] = 0.5f*vnw + 0.5f*vh;
}

// ---------------- bf16 MFMA causal flash attention ----------------
// Block: head h, q-blocks {bx*64, (31-bx)*64} (balanced: 33 kv-tiles per block).
// 4 waves x 16 q-rows. K,V staged swizzled; P round-trips per-wave LDS.
__global__ __launch_bounds__(256) void attn_mfma_k(
    const float* __restrict__ qkv, const __hip_bfloat16* __restrict__ kb,
    const __hip_bfloat16* __restrict__ vbT, __hip_bfloat16* __restrict__ yb)
{
  __shared__ __align__(16) char lds[24576];   // K 8KB | V 8KB | P 4x2KB
  const int h = blockIdx.y, bx = blockIdx.x, tid = threadIdx.x;
  const int w = tid>>6, l = tid&63, fr = l&15, fo = l>>4;
  const __hip_bfloat16* kbh = kb + (size_t)h*TT*64;
  const __hip_bfloat16* vbh = vbT + (size_t)h*64*TT;
  char* Kt = lds;
  char* Vt = lds + 8192;
  char* Pt = lds + 16384 + w*2048;

  int srow[2], schg[2];
#pragma unroll
  for (int r = 0; r < 2; ++r) {
    int s = r*256 + tid;
    srow[r] = s >> 3;
    schg[r] = (s & 7) ^ (srow[r] & 7);
  }

  for (int half = 0; half < 2; ++half) {
    const int qblk = half ? (31 - bx) : bx;
    const int q0 = qblk * 64;
    // Q fragments: fp32 -> bf16 in-register
    bf16x8 qa[2];
    {
      const float* qrow = qkv + (size_t)(q0 + w*16 + fr)*C3 + h*64;
#pragma unroll
      for (int kk = 0; kk < 2; ++kk) {
        float4 u0 = *(const float4*)(qrow + kk*32 + fo*8);
        float4 u1 = *(const float4*)(qrow + kk*32 + fo*8 + 4);
        bf16x8 t;
        t[0]=(__bf16)u0.x; t[1]=(__bf16)u0.y; t[2]=(__bf16)u0.z; t[3]=(__bf16)u0.w;
        t[4]=(__bf16)u1.x; t[5]=(__bf16)u1.y; t[6]=(__bf16)u1.z; t[7]=(__bf16)u1.w;
        qa[kk] = t;
      }
    }
    float mrow[4], lsum[4];
    f32x4 oacc[4];
#pragma unroll
    for (int e = 0; e < 4; ++e) { mrow[e] = -INFINITY; lsum[e] = 0.f; }
#pragma unroll
    for (int jv = 0; jv < 4; ++jv) oacc[jv] = f32x4{0.f,0.f,0.f,0.f};

    const int ntiles = qblk + 1;
    for (int kt = 0; kt < ntiles; ++kt) {
      uint4 rk[2], rv[2];
#pragma unroll
      for (int r = 0; r < 2; ++r) {
        rk[r] = *(const uint4*)(kbh + (size_t)(kt*64 + srow[r])*64 + schg[r]*8);
        rv[r] = *(const uint4*)(vbh + (size_t)srow[r]*TT + kt*64 + schg[r]*8);
      }
      __syncthreads();
#pragma unroll
      for (int r = 0; r < 2; ++r) {
        int s = r*256 + tid;
        *(uint4*)(Kt + s*16) = rk[r];
        *(uint4*)(Vt + s*16) = rv[r];
      }
      __syncthreads();

      // S = Q K^T  (col fr = key, row fo*4+e = q)
      f32x4 sv[4];
#pragma unroll
      for (int j = 0; j < 4; ++j) {
        int row = j*16 + fr;
        bf16x8 k0f = *(const bf16x8*)(Kt + row*128 + ((fo     ^ (row&7))*16));
        bf16x8 k1f = *(const bf16x8*)(Kt + row*128 + (((4+fo) ^ (row&7))*16));
        f32x4 z = {0.f,0.f,0.f,0.f};
        z = __builtin_amdgcn_mfma_f32_16x16x32_bf16(qa[0], k0f, z, 0,0,0);
        z = __builtin_amdgcn_mfma_f32_16x16x32_bf16(qa[1], k1f, z, 0,0,0);
        sv[j] = z;
      }
      if (kt == qblk) {
#pragma unroll
        for (int j = 0; j < 4; ++j)
#pragma unroll
          for (int e = 0; e < 4; ++e)
            sv[j][e] = (j*16 + fr <= w*16 + fo*4 + e) ? sv[j][e]*0.125f : -INFINITY;
      } else {
#pragma unroll
        for (int j = 0; j < 4; ++j)
#pragma unroll
          for (int e = 0; e < 4; ++e) sv[j][e] *= 0.125f;
      }
      // online softmax
      float rmax[4];
#pragma unroll
      for (int e = 0; e < 4; ++e)
        rmax[e] = fmaxf(fmaxf(sv[0][e], sv[1][e]), fmaxf(sv[2][e], sv[3][e]));
#pragma unroll
      for (int off = 1; off < 16; off <<= 1)
#pragma unroll
        for (int e = 0; e < 4; ++e) rmax[e] = fmaxf(rmax[e], __shfl_xor(rmax[e], off, 64));
      float scl[4];
#pragma unroll
      for (int e = 0; e < 4; ++e) {
        float mn = fmaxf(mrow[e], rmax[e]);
        scl[e] = __expf(mrow[e] - mn);
        mrow[e] = mn;
      }
      float rsum[4] = {0.f,0.f,0.f,0.f};
#pragma unroll
      for (int j = 0; j < 4; ++j) {
        int chunkbase = j*2 + (fr>>3);
        int kvoff = (fr&7)*2;
#pragma unroll
        for (int e = 0; e < 4; ++e) {
          float p = __expf(sv[j][e] - mrow[e]);
          rsum[e] += p;
          int qloc = fo*4 + e;
          *(__bf16*)(Pt + qloc*128 + ((chunkbase ^ (qloc&7))*16) + kvoff) = (__bf16)p;
        }
      }
#pragma unroll
      for (int off = 1; off < 16; off <<= 1)
#pragma unroll
        for (int e = 0; e < 4; ++e) rsum[e] += __shfl_xor(rsum[e], off, 64);
#pragma unroll
      for (int e = 0; e < 4; ++e) lsum[e] = lsum[e]*scl[e] + rsum[e];
#pragma unroll
      for (int jv = 0; jv < 4; ++jv)
#pragma unroll
        for (int e = 0; e < 4; ++e) oacc[jv][e] *= scl[e];

      // PV: A = P (row fr = q, from Pt), B = V^T tile
      bf16x8 pa0 = *(const bf16x8*)(Pt + fr*128 + ((fo     ^ (fr&7))*16));
      bf16x8 pa1 = *(const bf16x8*)(Pt + fr*128 + (((4+fo) ^ (fr&7))*16));
#pragma unroll
      for (int jv = 0; jv < 4; ++jv) {
        int row = jv*16 + fr;
        bf16x8 v0f = *(const bf16x8*)(Vt + row*128 + ((fo     ^ (row&7))*16));
        bf16x8 v1f = *(const bf16x8*)(Vt + row*128 + (((4+fo) ^ (row&7))*16));
        oacc[jv] = __builtin_amdgcn_mfma_f32_16x16x32_bf16(pa0, v0f, oacc[jv], 0,0,0);
        oacc[jv] = __builtin_amdgcn_mfma_f32_16x16x32_bf16(pa1, v1f, oacc[jv], 0,0,0);
      }
    }
    // epilogue: y (bf16) row t, col h*64 + jv*16 + fr
#pragma unroll
    for (int jv = 0; jv < 4; ++jv)
#pragma unroll
      for (int e = 0; e < 4; ++e) {
        int t = q0 + w*16 + fo*4 + e;
        yb[(size_t)t*CC + h*64 + jv*16 + fr] = __float2bfloat16(oacc[jv][e] / lsum[e]);
      }
  }
}

extern "C" void kernel_launch(void* const* d_in, const int* in_sizes, int n_in,
                              void* d_out, int out_size, void* d_ws, size_t ws_size,
                              hipStream_t stream) {
  const float* x   = (const float*)d_in[0];
  const float* wat = (const float*)d_in[1];
  const float* wpr = (const float*)d_in[2];
  const float* kst = (const float*)d_in[3];
  const float* vst = (const float*)d_in[4];
  float* out = (float*)d_out;

  // workspace (float slots), total ~16.2M fs (~65MB)
  float* ws    = (float*)d_ws;
  float* qkv   = ws;                                   // 6291456
  float* ksn   = qkv + (size_t)6291456;                // 131072
  float* ksnb  = ksn + 131072;                         // 131072
  int*   idxb  = (int*)(ksnb + 131072);                // 131072
  int*   maskb = idxb + 131072;                        // 32768
  __hip_bfloat16* kb = (__hip_bfloat16*)(maskb + 32768);       // 2097152 bf16
  float* candRegion = (float*)kb + 1048576;            // 2097152 (cand u32 / vnew f32)
  unsigned int* candb = (unsigned int*)candRegion;
  float* vnew = candRegion;
  __hip_bfloat16* vbT = (__hip_bfloat16*)(candRegion + 2097152); // 2097152 bf16
  float* split = candRegion + 2097152 + 1048576;       // 5242880 fs region
  // phase 1: x/w hi-lo splits
  __hip_bfloat16* xhi = (__hip_bfloat16*)split;        // 2097152 bf16
  __hip_bfloat16* xlo = xhi + 2097152;
  __hip_bfloat16* whi = xlo + 2097152;                 // 3145728 bf16
  __hip_bfloat16* wlo = whi + 3145728;
  // phase 2 aliases (after qkv GEMM): ksb | wprb ; phase 3 (after chunkmin): yb
  __hip_bfloat16* ksb  = (__hip_bfloat16*)split;       // 8388608 bf16
  __hip_bfloat16* wprb = ksb + 8388608;                // 1048576 bf16
  __hip_bfloat16* yb   = (__hip_bfloat16*)split;       // 2097152 bf16

  // 1-2. hi/lo splits of x and c_attn_w
  conv_split_k<<<dim3(1024), 256, 0, stream>>>(x, xhi, xlo);
  conv_split_k<<<dim3(1536), 256, 0, stream>>>(wat, whi, wlo);
  // 3. qkv = x @ c_attn_w^T  (bf16x3 MFMA, fp32-fidelity)
  gemm_mfma_k<true><<<dim3(16*24), 256, 0, stream>>>(xhi, xlo, whi, wlo, qkv, TT, C3, CC);
  // 4. k -> bf16 [h][t][d]
  conv_kb_k<<<dim3(1024), 256, 0, stream>>>(qkv, kb);
  // 5. key_store -> bf16 + norms (into split region; x/w splits dead now)
  conv_ks_k<<<dim3(HH*MM/4), 256, 0, stream>>>(kst, ksb, ksn, ksnb);
  // 6. c_proj_w -> bf16
  conv_bf16_k<<<dim3(512), 256, 0, stream>>>(wpr, wprb);
  // 7. mask (exact fp32)
  attlast_mask_k<<<dim3(HH), 256, 0, stream>>>(qkv, maskb);
  // 8. phase A: MFMA chunk-min scoring
  knn_chunkmin_k<<<dim3(512), 256, 0, stream>>>(kb, ksb, ksnb, candb);
  // 9. phase B: exact rescore -> top-4
  knn_select_k<<<dim3(HH*TT/4), 256, 0, stream>>>(candb, qkv, kst, ksn, idxb);
  // 10. v_new (fp32; vnew aliases cand - consumed)
  knn_apply_k<<<dim3(HH*TT/4), 256, 0, stream>>>(qkv, kst, vst, idxb, maskb, vnew);
  // 11. v_new -> transposed bf16 [h][dv][t]
  vtrans_k<<<dim3(32, HH), 256, 0, stream>>>(vnew, vbT);
  // 12. causal flash attention (yb aliases ksb - consumed)
  attn_mfma_k<<<dim3(16, HH), 256, 0, stream>>>(qkv, kb, vbT, yb);
  // 13. out = y @ c_proj_w^T (plain bf16 MFMA)
  gemm_mfma_k<false><<<dim3(16*8), 256, 0, stream>>>(yb, nullptr, wprb, nullptr, out, TT, CC, CC);
}

// Round 4
// 352.391 us; speedup vs baseline: 5.1361x; 1.5208x over previous
//
#include <hip/hip_runtime.h>
#include <hip/hip_bf16.h>
#include <math.h>

#define TT 2048
#define CC 1024
#define HH 16
#define DDIM 64
#define MM 8192
#define C3 3072
#define SBIAS 256.0f

#define LTPAIR(sa,ma,sb,mb) ((sa) < (sb) || ((sa) == (sb) && (ma) < (mb)))

typedef __bf16 bf16x8 __attribute__((ext_vector_type(8)));
typedef float f32x4 __attribute__((ext_vector_type(4)));

__device__ __forceinline__ float waveReduceSum(float v) {
#pragma unroll
  for (int off = 32; off > 0; off >>= 1) v += __shfl_xor(v, off, 64);
  return v;
}
__device__ __forceinline__ unsigned waveMinU32(unsigned v) {
#pragma unroll
  for (int off = 32; off > 0; off >>= 1) {
    unsigned o = __shfl_xor(v, off, 64);
    v = (o < v) ? o : v;
  }
  return v;
}
__device__ __forceinline__ unsigned umn(unsigned a, unsigned b){ return a<b?a:b; }
__device__ __forceinline__ unsigned umx(unsigned a, unsigned b){ return a>b?a:b; }

// async global->LDS, 16B per lane. lds dest must be wave-uniform base (+lane*16 by HW);
// global src is per-lane (carries our chunk pre-swizzle).
__device__ __forceinline__ void gload16(const void* g, void* l) {
  __builtin_amdgcn_global_load_lds(
      (const __attribute__((address_space(1))) unsigned int*)g,
      (__attribute__((address_space(3))) unsigned int*)l, 16, 0, 0);
}

// ---------------- conversions ----------------
__global__ __launch_bounds__(256) void conv_split_k(const float* __restrict__ src,
    __hip_bfloat16* __restrict__ hi, __hip_bfloat16* __restrict__ lo)
{
  size_t i = (size_t)blockIdx.x*256 + threadIdx.x;
  const float4* p = (const float4*)(src + i*8);
  float4 a = p[0], b = p[1];
  float v[8] = {a.x,a.y,a.z,a.w,b.x,b.y,b.z,b.w};
  bf16x8 H, L;
#pragma unroll
  for (int e = 0; e < 8; ++e) {
    __bf16 hb = (__bf16)v[e];
    H[e] = hb;
    L[e] = (__bf16)(v[e] - (float)hb);
  }
  *reinterpret_cast<bf16x8*>(hi + i*8) = H;
  *reinterpret_cast<bf16x8*>(lo + i*8) = L;
}

__global__ __launch_bounds__(256) void conv_bf16_k(const float* __restrict__ src,
    __hip_bfloat16* __restrict__ dst)
{
  size_t i = (size_t)blockIdx.x*256 + threadIdx.x;
  const float4* p = (const float4*)(src + i*8);
  float4 a = p[0], b = p[1];
  float v[8] = {a.x,a.y,a.z,a.w,b.x,b.y,b.z,b.w};
  bf16x8 H;
#pragma unroll
  for (int e = 0; e < 8; ++e) H[e] = (__bf16)v[e];
  *reinterpret_cast<bf16x8*>(dst + i*8) = H;
}

__global__ __launch_bounds__(256) void conv_ks_k(const float* __restrict__ ks,
    __hip_bfloat16* __restrict__ ksb, float* __restrict__ ksn, float* __restrict__ ksnb)
{
  int row = blockIdx.x*4 + (threadIdx.x>>6);   // HH*MM rows
  int lane = threadIdx.x & 63;
  float v = ks[(size_t)row*64 + lane];
  float sq = waveReduceSum(v*v);
  ksb[(size_t)row*64 + lane] = __float2bfloat16(v);
  if (lane == 0) { ksn[row] = sq; ksnb[row] = sq + SBIAS; }
}

__global__ __launch_bounds__(256) void conv_kb_k(const float* __restrict__ qkv,
    __hip_bfloat16* __restrict__ kb)
{
  int e = blockIdx.x*256 + threadIdx.x;
  int dg = e & 7; int t = (e>>3) & (TT-1); int h = e >> 14;
  const float* src = qkv + (size_t)t*C3 + CC + h*64 + dg*8;
  __hip_bfloat16* dst = kb + ((size_t)(h*TT + t)*64 + dg*8);
#pragma unroll
  for (int i = 0; i < 8; ++i) dst[i] = __float2bfloat16(src[i]);
}

__global__ __launch_bounds__(256) void vtrans_k(const float* __restrict__ vnew,
    __hip_bfloat16* __restrict__ vbT)
{
  __shared__ float tbuf[64][65];
  const int h = blockIdx.y, t0 = blockIdx.x*64, tid = threadIdx.x;
#pragma unroll
  for (int r = 0; r < 16; ++r) {
    int e = r*256 + tid; int row = e>>6, dv = e&63;
    tbuf[row][dv] = vnew[((size_t)h*TT + t0 + row)*64 + dv];
  }
  __syncthreads();
#pragma unroll
  for (int r = 0; r < 16; ++r) {
    int e = r*256 + tid; int dv = e>>6, tt = e&63;
    vbT[((size_t)h*64 + dv)*TT + t0 + tt] = __float2bfloat16(tbuf[tt][dv]);
  }
}

// ---------------- MFMA GEMM: C[m][n] = sum_k A[m][k]*B[n][k] ----------------
// 2-phase pipeline: double-buffered LDS, global_load_lds staging (linear dest,
// pre-XOR-swizzled source chunks), one barrier per K-step, LDS-transposed epilogue.
template<bool SPLIT>
__global__ __launch_bounds__(256) void gemm_mfma_k(
    const __hip_bfloat16* __restrict__ Ah, const __hip_bfloat16* __restrict__ Al,
    const __hip_bfloat16* __restrict__ Bh, const __hip_bfloat16* __restrict__ Bl,
    float* __restrict__ Cc, int M, int N, int K)
{
  __shared__ __align__(16) char lds[2][32768];   // per buf: A [128][128B] | B [128][128B]
  const int tid = threadIdx.x;
  const int nbx = N >> 7;
  const int by = blockIdx.x / nbx, bx = blockIdx.x - by*nbx;
  const int m0 = by << 7, n0 = bx << 7;
  const int w = tid >> 6;
  const int l = tid & 63;
  const int wslot = w << 6;
  const int wi = w >> 1, wj = w & 1;
  const int fr = l & 15, fo = l >> 4;
  const int kw = SPLIT ? 32 : 64;
  const int nsteps = K / kw;

  f32x4 acc[4][4];
#pragma unroll
  for (int i = 0; i < 4; ++i)
#pragma unroll
    for (int j = 0; j < 4; ++j) acc[i][j] = f32x4{0.f,0.f,0.f,0.f};

  int srow[4], schg[4];
#pragma unroll
  for (int r = 0; r < 4; ++r) {
    int s = r*256 + tid;
    srow[r] = s >> 3;
    schg[r] = (s & 7) ^ (srow[r] & 7);
  }

  auto stageAB = [&](int buf, int st) {
    const int k0 = st * kw;
#pragma unroll
    for (int r = 0; r < 4; ++r) {
      const __hip_bfloat16 *pa, *pb;
      if (SPLIT) {
        pa = (schg[r] < 4 ? Ah : Al) + (size_t)(m0+srow[r])*K + k0 + (schg[r]&3)*8;
        pb = (schg[r] < 4 ? Bh : Bl) + (size_t)(n0+srow[r])*K + k0 + (schg[r]&3)*8;
      } else {
        pa = Ah + (size_t)(m0+srow[r])*K + k0 + schg[r]*8;
        pb = Bh + (size_t)(n0+srow[r])*K + k0 + schg[r]*8;
      }
      gload16(pa, lds[buf] + (r*256 + wslot)*16);
      gload16(pb, lds[buf] + 16384 + (r*256 + wslot)*16);
    }
  };

  stageAB(0, 0);
  __syncthreads();

  for (int st = 0; st < nsteps; ++st) {
    const int buf = st & 1;
    if (st + 1 < nsteps) stageAB(buf ^ 1, st + 1);
    char* ldsb = lds[buf];

    if (SPLIT) {
      bf16x8 bhf[4], blf[4];
#pragma unroll
      for (int j = 0; j < 4; ++j) {
        int row = wj*64 + j*16 + fr;
        bhf[j] = *(const bf16x8*)(ldsb + 16384 + row*128 + ((fo     ^ (row&7))*16));
        blf[j] = *(const bf16x8*)(ldsb + 16384 + row*128 + (((4+fo) ^ (row&7))*16));
      }
#pragma unroll
      for (int i = 0; i < 4; ++i) {
        int row = wi*64 + i*16 + fr;
        bf16x8 ah = *(const bf16x8*)(ldsb + row*128 + ((fo     ^ (row&7))*16));
        bf16x8 al = *(const bf16x8*)(ldsb + row*128 + (((4+fo) ^ (row&7))*16));
#pragma unroll
        for (int j = 0; j < 4; ++j) {
          acc[i][j] = __builtin_amdgcn_mfma_f32_16x16x32_bf16(al, bhf[j], acc[i][j], 0,0,0);
          acc[i][j] = __builtin_amdgcn_mfma_f32_16x16x32_bf16(ah, blf[j], acc[i][j], 0,0,0);
          acc[i][j] = __builtin_amdgcn_mfma_f32_16x16x32_bf16(ah, bhf[j], acc[i][j], 0,0,0);
        }
      }
    } else {
#pragma unroll
      for (int kk = 0; kk < 2; ++kk) {
        bf16x8 bf[4];
#pragma unroll
        for (int j = 0; j < 4; ++j) {
          int row = wj*64 + j*16 + fr;
          bf[j] = *(const bf16x8*)(ldsb + 16384 + row*128 + (((kk*4+fo) ^ (row&7))*16));
        }
#pragma unroll
        for (int i = 0; i < 4; ++i) {
          int row = wi*64 + i*16 + fr;
          bf16x8 af = *(const bf16x8*)(ldsb + row*128 + (((kk*4+fo) ^ (row&7))*16));
#pragma unroll
          for (int j = 0; j < 4; ++j)
            acc[i][j] = __builtin_amdgcn_mfma_f32_16x16x32_bf16(af, bf[j], acc[i][j], 0,0,0);
        }
      }
    }
    __syncthreads();   // drains this step's async stages (vmcnt 0) + barrier
  }

  // epilogue: per-wave LDS transpose -> float4 row stores (256B segments)
  float* ep = (float*)((char*)lds + (size_t)w*8704);   // 32 rows x 68 floats
#pragma unroll
  for (int pass = 0; pass < 2; ++pass) {
#pragma unroll
    for (int ii = 0; ii < 2; ++ii) {
      int i = pass*2 + ii;
#pragma unroll
      for (int j = 0; j < 4; ++j)
#pragma unroll
        for (int e = 0; e < 4; ++e)
          ep[(ii*16 + fo*4 + e)*68 + j*16 + fr] = acc[i][j][e];
    }
#pragma unroll
    for (int eidx = 0; eidx < 8; ++eidx) {
      int fi = eidx*64 + l;
      int row = fi >> 4, c4 = fi & 15;
      float4 v4 = *(const float4*)(ep + row*68 + c4*4);
      *(float4*)(Cc + (size_t)(m0 + wi*64 + pass*32 + row)*N + n0 + wj*64 + c4*4) = v4;
    }
  }
}

// ---------------- exact fp32 softmax of last attention row -> mask ----------------
__global__ __launch_bounds__(256) void attlast_mask_k(const float* __restrict__ qkv, int* __restrict__ mask)
{
  const int h = blockIdx.x;
  __shared__ float ql[64];
  __shared__ float lg[TT];
  __shared__ float red[256];
  const int tid = threadIdx.x;
  if (tid < 64) ql[tid] = qkv[(size_t)(TT-1)*C3 + h*DDIM + tid];
  __syncthreads();
  float lmax = -INFINITY;
  for (int t = tid; t < TT; t += 256) {
    const float* kr = qkv + (size_t)t*C3 + CC + h*DDIM;
    float s = 0.f;
#pragma unroll
    for (int d = 0; d < 64; ++d) s += ql[d] * kr[d];
    s *= 0.125f;
    lg[t] = s;
    lmax = fmaxf(lmax, s);
  }
  red[tid] = lmax; __syncthreads();
  for (int off = 128; off > 0; off >>= 1) { if (tid < off) red[tid] = fmaxf(red[tid], red[tid+off]); __syncthreads(); }
  float mx = red[0];
  __syncthreads();
  float ls = 0.f;
  for (int t = tid; t < TT; t += 256) { float e = expf(lg[t]-mx); lg[t] = e; ls += e; }
  red[tid] = ls; __syncthreads();
  for (int off = 128; off > 0; off >>= 1) { if (tid < off) red[tid] += red[tid+off]; __syncthreads(); }
  float Z = red[0];
  for (int t = tid; t < TT; t += 256) mask[h*TT + t] = (lg[t]/Z >= 1.220703125e-4f) ? 1 : 0;
}

// ---------------- phase A: bf16 MFMA scoring + per-cell top-4 chunk-mins ----------------
__global__ __launch_bounds__(256) void knn_chunkmin_k(
    const __hip_bfloat16* __restrict__ kb, const __hip_bfloat16* __restrict__ ksb,
    const float* __restrict__ ksnb, unsigned int* __restrict__ cand)
{
  __shared__ __align__(16) char lds[2*8192];
  const int tid = threadIdx.x;
  const int bid = blockIdx.x;
  const int orig = (bid & 7)*64 + (bid >> 3);
  const int h  = orig >> 5;
  const int n0 = (orig & 31) * 64;
  const int w  = tid >> 6;
  const int l  = tid & 63;
  const int cr = l & 15, hi = l >> 4;

  bf16x8 af0, af1;
  {
    const __hip_bfloat16* kbh = kb + (size_t)h*TT*64 + (size_t)(n0 + w*16 + cr)*64;
    af0 = *reinterpret_cast<const bf16x8*>(kbh + 0*32 + hi*8);
    af1 = *reinterpret_cast<const bf16x8*>(kbh + 1*32 + hi*8);
  }
  const __hip_bfloat16* ksbh = ksb + (size_t)h*MM*64;
  const float* ksnh = ksnb + (size_t)h*MM;

  const int c0 = tid*2, c1 = tid*2 + 1;
  const int wb0 = (c0>>3)*128 + (((c0&7) ^ ((c0>>3)&7))*16);
  const int wb1 = (c1>>3)*128 + (((c1&7) ^ ((c1>>3)&7))*16);
  const int rb0 = (l&15)*128 + (((0 + hi) ^ (l&7))*16);
  const int rb1 = (l&15)*128 + (((4 + hi) ^ (l&7))*16);

  unsigned cnd[4][4];
#pragma unroll
  for (int i = 0; i < 4; ++i)
#pragma unroll
    for (int c = 0; c < 4; ++c) cnd[i][c] = 0xFFFFFFFFu;

  uint4 r0, r1;
  {
    const uint4* g = reinterpret_cast<const uint4*>(ksbh);
    r0 = g[c0]; r1 = g[c1];
    *reinterpret_cast<uint4*>(lds + wb0) = r0;
    *reinterpret_cast<uint4*>(lds + wb1) = r1;
  }

  for (int tt = 0; tt < 128; ++tt) {
    __syncthreads();
    const int buf = tt & 1;
    char* ldsb = lds + buf*8192;
    if (tt + 1 < 128) {
      const uint4* g = reinterpret_cast<const uint4*>(ksbh + (size_t)(tt+1)*64*64);
      r0 = g[c0]; r1 = g[c1];
    }
    float kn0 = ksnh[tt*64 +  0 + cr];
    float kn1 = ksnh[tt*64 + 16 + cr];
    float kn2 = ksnh[tt*64 + 32 + cr];
    float kn3 = ksnh[tt*64 + 48 + cr];

    f32x4 acc[4];
#pragma unroll
    for (int b = 0; b < 4; ++b) {
      bf16x8 bf0 = *reinterpret_cast<const bf16x8*>(ldsb + b*2048 + rb0);
      bf16x8 bf1 = *reinterpret_cast<const bf16x8*>(ldsb + b*2048 + rb1);
      f32x4 z = {0.f, 0.f, 0.f, 0.f};
      z = __builtin_amdgcn_mfma_f32_16x16x32_bf16(af0, bf0, z, 0, 0, 0);
      z = __builtin_amdgcn_mfma_f32_16x16x32_bf16(af1, bf1, z, 0, 0, 0);
      acc[b] = z;
    }
#pragma unroll
    for (int i = 0; i < 4; ++i) {
      float s0 = fmaf(acc[0][i], -2.f, kn0);
      float s1 = fmaf(acc[1][i], -2.f, kn1);
      float s2 = fmaf(acc[2][i], -2.f, kn2);
      float s3 = fmaf(acc[3][i], -2.f, kn3);
      float m4 = fminf(fminf(s0, s1), fminf(s2, s3));
      unsigned x = (__float_as_uint(m4) & 0xFFFFFF80u) | (unsigned)tt;
      unsigned tmp;
      tmp = umn(cnd[i][0], x); x = umx(cnd[i][0], x); cnd[i][0] = tmp;
      tmp = umn(cnd[i][1], x); x = umx(cnd[i][1], x); cnd[i][1] = tmp;
      tmp = umn(cnd[i][2], x); x = umx(cnd[i][2], x); cnd[i][2] = tmp;
      cnd[i][3] = umn(cnd[i][3], x);
    }
    if (tt + 1 < 128) {
      char* ldsn = lds + (buf^1)*8192;
      *reinterpret_cast<uint4*>(ldsn + wb0) = r0;
      *reinterpret_cast<uint4*>(ldsn + wb1) = r1;
    }
  }

#pragma unroll
  for (int i = 0; i < 4; ++i) {
    int n = n0 + w*16 + hi*4 + i;
    reinterpret_cast<uint4*>(cand)[(size_t)(h*TT + n)*16 + cr] =
        make_uint4(cnd[i][0], cnd[i][1], cnd[i][2], cnd[i][3]);
  }
}

// ---------------- phase B: top-8 chunks -> exact fp32 rescore -> top-4 ----------------
__global__ __launch_bounds__(256) void knn_select_k(
    const unsigned int* __restrict__ cand, const float* __restrict__ qkv,
    const float* __restrict__ kstore, const float* __restrict__ ksn,
    int* __restrict__ idxout)
{
  const int row = blockIdx.x*4 + (threadIdx.x>>6);
  const int l = threadIdx.x & 63;
  const int h = row >> 11, t = row & (TT-1);
  unsigned v = cand[(size_t)row*64 + (l&15)*4 + (l>>4)];
  const float kreg = qkv[(size_t)t*C3 + CC + h*64 + l];
  const float* ksh = kstore + (size_t)h*MM*64;
  const float* ksnh = ksn + (size_t)h*MM;

  float bs0=3.4e38f, bs1=3.4e38f, bs2=3.4e38f, bs3=3.4e38f;
  int bm0=0x7fffffff, bm1=0x7fffffff, bm2=0x7fffffff, bm3=0x7fffffff;

  for (int it = 0; it < 8; ++it) {
    unsigned mv = waveMinU32(v);
    if (mv == 0xFFFFFFFFu) break;
    unsigned long long ball = __ballot(v == mv);
    int src = __ffsll(ball) - 1;
    int tIdx = (int)(mv & 127u);
    int crw = src & 15;
    if (l == src) v = 0xFFFFFFFFu;
#pragma unroll
    for (int b = 0; b < 4; ++b) {
      int m = tIdx*64 + b*16 + crw;
      float ksv = ksh[(size_t)m*64 + l];
      float dot = waveReduceSum(kreg * ksv);
      float s = ksnh[m] - 2.f*dot;
      if (LTPAIR(s,m, bs3,bm3)) {
        if (LTPAIR(s,m, bs1,bm1)) {
          bs3=bs2; bm3=bm2; bs2=bs1; bm2=bm1;
          if (LTPAIR(s,m, bs0,bm0)) { bs1=bs0; bm1=bm0; bs0=s; bm0=m; }
          else { bs1=s; bm1=m; }
        } else {
          if (LTPAIR(s,m, bs2,bm2)) { bs3=bs2; bm3=bm2; bs2=s; bm2=m; }
          else { bs3=s; bm3=m; }
        }
      }
    }
  }
  if (l == 0) {
    int* o = idxout + (size_t)row*4;
    o[0]=bm0; o[1]=bm1; o[2]=bm2; o[3]=bm3;
  }
}

// ---------------- build v_new ----------------
__global__ __launch_bounds__(256) void knn_apply_k(
    const float* __restrict__ qkv, const float* __restrict__ kstore, const float* __restrict__ vstore,
    const int* __restrict__ idx, const int* __restrict__ mask, float* __restrict__ vnew)
{
  const int r = blockIdx.x * 4 + (threadIdx.x >> 6);
  const int lane = threadIdx.x & 63;
  const int h = r >> 11, t = r & (TT-1);
  const float* base = qkv + (size_t)t*C3 + h*DDIM;
  float vh = base[2*CC + lane];
  float* outp = vnew + ((size_t)h*TT + t)*DDIM;
  if (!mask[r]) { outp[lane] = vh; return; }
  float qd = base[lane];
  float kd = base[CC + lane];
  float s0 = waveReduceSum(qd*kd) * 0.125f;
  float sj[4], vj[4];
#pragma unroll
  for (int j = 0; j < 4; ++j) {
    int m = idx[(size_t)r*4 + j];
    const float* kp = kstore + ((size_t)h*MM + m)*DDIM;
    const float* vp = vstore + ((size_t)h*MM + m)*DDIM;
    sj[j] = waveReduceSum(qd * kp[lane]) * 0.125f;
    vj[j] = vp[lane];
  }
  float mx = fmaxf(fmaxf(fmaxf(s0,sj[0]),fmaxf(sj[1],sj[2])),sj[3]);
  float w0 = expf(s0-mx), w1 = expf(sj[0]-mx), w2 = expf(sj[1]-mx), w3 = expf(sj[2]-mx), w4 = expf(sj[3]-mx);
  float Z = w0+w1+w2+w3+w4;
  float vnw = (w0*vh + w1*vj[0] + w2*vj[1] + w3*vj[2] + w4*vj[3]) / Z;
  outp[lane] = 0.5f*vnw + 0.5f*vh;
}

// ---------------- bf16 MFMA causal flash attention (2-phase gload_lds pipeline) ----------------
__global__ __launch_bounds__(256) void attn_mfma_k(
    const float* __restrict__ qkv, const __hip_bfloat16* __restrict__ kb,
    const __hip_bfloat16* __restrict__ vbT, __hip_bfloat16* __restrict__ yb)
{
  __shared__ __align__(16) char lds[40960];   // 2 x (K 8KB | V 8KB) | P 4x2KB
  const int h = blockIdx.y, bx = blockIdx.x, tid = threadIdx.x;
  const int w = tid>>6, l = tid&63, fr = l&15, fo = l>>4;
  const int wslot = w << 6;
  const __hip_bfloat16* kbh = kb + (size_t)h*TT*64;
  const __hip_bfloat16* vbh = vbT + (size_t)h*64*TT;
  char* Pt = lds + 32768 + w*2048;

  int srow[2], schg[2];
#pragma unroll
  for (int r = 0; r < 2; ++r) {
    int s = r*256 + tid;
    srow[r] = s >> 3;
    schg[r] = (s & 7) ^ (srow[r] & 7);
  }

  auto stageKV = [&](int buf, int kt) {
#pragma unroll
    for (int r = 0; r < 2; ++r) {
      gload16(kbh + (size_t)(kt*64 + srow[r])*64 + schg[r]*8,
              lds + buf*16384 + (r*256 + wslot)*16);
      gload16(vbh + (size_t)srow[r]*TT + kt*64 + schg[r]*8,
              lds + buf*16384 + 8192 + (r*256 + wslot)*16);
    }
  };

  for (int half = 0; half < 2; ++half) {
    const int qblk = half ? (31 - bx) : bx;
    const int q0 = qblk * 64;
    bf16x8 qa[2];
    {
      const float* qrow = qkv + (size_t)(q0 + w*16 + fr)*C3 + h*64;
#pragma unroll
      for (int kk = 0; kk < 2; ++kk) {
        float4 u0 = *(const float4*)(qrow + kk*32 + fo*8);
        float4 u1 = *(const float4*)(qrow + kk*32 + fo*8 + 4);
        bf16x8 t;
        t[0]=(__bf16)u0.x; t[1]=(__bf16)u0.y; t[2]=(__bf16)u0.z; t[3]=(__bf16)u0.w;
        t[4]=(__bf16)u1.x; t[5]=(__bf16)u1.y; t[6]=(__bf16)u1.z; t[7]=(__bf16)u1.w;
        qa[kk] = t;
      }
    }
    float mrow[4], lsum[4];
    f32x4 oacc[4];
#pragma unroll
    for (int e = 0; e < 4; ++e) { mrow[e] = -INFINITY; lsum[e] = 0.f; }
#pragma unroll
    for (int jv = 0; jv < 4; ++jv) oacc[jv] = f32x4{0.f,0.f,0.f,0.f};

    const int ntiles = qblk + 1;
    stageKV(0, 0);
    __syncthreads();

    for (int kt = 0; kt < ntiles; ++kt) {
      const int buf = kt & 1;
      if (kt + 1 < ntiles) stageKV(buf ^ 1, kt + 1);
      char* Kt = lds + buf*16384;
      char* Vt = Kt + 8192;

      f32x4 sv[4];
#pragma unroll
      for (int j = 0; j < 4; ++j) {
        int row = j*16 + fr;
        bf16x8 k0f = *(const bf16x8*)(Kt + row*128 + ((fo     ^ (row&7))*16));
        bf16x8 k1f = *(const bf16x8*)(Kt + row*128 + (((4+fo) ^ (row&7))*16));
        f32x4 z = {0.f,0.f,0.f,0.f};
        z = __builtin_amdgcn_mfma_f32_16x16x32_bf16(qa[0], k0f, z, 0,0,0);
        z = __builtin_amdgcn_mfma_f32_16x16x32_bf16(qa[1], k1f, z, 0,0,0);
        sv[j] = z;
      }
      if (kt == qblk) {
#pragma unroll
        for (int j = 0; j < 4; ++j)
#pragma unroll
          for (int e = 0; e < 4; ++e)
            sv[j][e] = (j*16 + fr <= w*16 + fo*4 + e) ? sv[j][e]*0.125f : -INFINITY;
      } else {
#pragma unroll
        for (int j = 0; j < 4; ++j)
#pragma unroll
          for (int e = 0; e < 4; ++e) sv[j][e] *= 0.125f;
      }
      float rmax[4];
#pragma unroll
      for (int e = 0; e < 4; ++e)
        rmax[e] = fmaxf(fmaxf(sv[0][e], sv[1][e]), fmaxf(sv[2][e], sv[3][e]));
#pragma unroll
      for (int off = 1; off < 16; off <<= 1)
#pragma unroll
        for (int e = 0; e < 4; ++e) rmax[e] = fmaxf(rmax[e], __shfl_xor(rmax[e], off, 64));
      float scl[4];
#pragma unroll
      for (int e = 0; e < 4; ++e) {
        float mn = fmaxf(mrow[e], rmax[e]);
        scl[e] = __expf(mrow[e] - mn);
        mrow[e] = mn;
      }
      float rsum[4] = {0.f,0.f,0.f,0.f};
#pragma unroll
      for (int j = 0; j < 4; ++j) {
        int chunkbase = j*2 + (fr>>3);
        int kvoff = (fr&7)*2;
#pragma unroll
        for (int e = 0; e < 4; ++e) {
          float p = __expf(sv[j][e] - mrow[e]);
          rsum[e] += p;
          int qloc = fo*4 + e;
          *(__bf16*)(Pt + qloc*128 + ((chunkbase ^ (qloc&7))*16) + kvoff) = (__bf16)p;
        }
      }
#pragma unroll
      for (int off = 1; off < 16; off <<= 1)
#pragma unroll
        for (int e = 0; e < 4; ++e) rsum[e] += __shfl_xor(rsum[e], off, 64);
#pragma unroll
      for (int e = 0; e < 4; ++e) lsum[e] = lsum[e]*scl[e] + rsum[e];
#pragma unroll
      for (int jv = 0; jv < 4; ++jv)
#pragma unroll
        for (int e = 0; e < 4; ++e) oacc[jv][e] *= scl[e];

      bf16x8 pa0 = *(const bf16x8*)(Pt + fr*128 + ((fo     ^ (fr&7))*16));
      bf16x8 pa1 = *(const bf16x8*)(Pt + fr*128 + (((4+fo) ^ (fr&7))*16));
#pragma unroll
      for (int jv = 0; jv < 4; ++jv) {
        int row = jv*16 + fr;
        bf16x8 v0f = *(const bf16x8*)(Vt + row*128 + ((fo     ^ (row&7))*16));
        bf16x8 v1f = *(const bf16x8*)(Vt + row*128 + (((4+fo) ^ (row&7))*16));
        oacc[jv] = __builtin_amdgcn_mfma_f32_16x16x32_bf16(pa0, v0f, oacc[jv], 0,0,0);
        oacc[jv] = __builtin_amdgcn_mfma_f32_16x16x32_bf16(pa1, v1f, oacc[jv], 0,0,0);
      }
      __syncthreads();   // drains async stages + protects both LDS buffers
    }
#pragma unroll
    for (int jv = 0; jv < 4; ++jv)
#pragma unroll
      for (int e = 0; e < 4; ++e) {
        int t = q0 + w*16 + fo*4 + e;
        yb[(size_t)t*CC + h*64 + jv*16 + fr] = __float2bfloat16(oacc[jv][e] / lsum[e]);
      }
  }
}

extern "C" void kernel_launch(void* const* d_in, const int* in_sizes, int n_in,
                              void* d_out, int out_size, void* d_ws, size_t ws_size,
                              hipStream_t stream) {
  const float* x   = (const float*)d_in[0];
  const float* wat = (const float*)d_in[1];
  const float* wpr = (const float*)d_in[2];
  const float* kst = (const float*)d_in[3];
  const float* vst = (const float*)d_in[4];
  float* out = (float*)d_out;

  float* ws    = (float*)d_ws;
  float* qkv   = ws;                                   // 6291456
  float* ksn   = qkv + (size_t)6291456;                // 131072
  float* ksnb  = ksn + 131072;                         // 131072
  int*   idxb  = (int*)(ksnb + 131072);                // 131072
  int*   maskb = idxb + 131072;                        // 32768
  __hip_bfloat16* kb = (__hip_bfloat16*)(maskb + 32768);       // 2097152 bf16
  float* candRegion = (float*)kb + 1048576;            // 2097152 (cand u32 / vnew f32)
  unsigned int* candb = (unsigned int*)candRegion;
  float* vnew = candRegion;
  __hip_bfloat16* vbT = (__hip_bfloat16*)(candRegion + 2097152); // 2097152 bf16
  float* split = candRegion + 2097152 + 1048576;       // 5242880 fs region
  __hip_bfloat16* xhi = (__hip_bfloat16*)split;
  __hip_bfloat16* xlo = xhi + 2097152;
  __hip_bfloat16* whi = xlo + 2097152;
  __hip_bfloat16* wlo = whi + 3145728;
  __hip_bfloat16* ksb  = (__hip_bfloat16*)split;
  __hip_bfloat16* wprb = ksb + 8388608;
  __hip_bfloat16* yb   = (__hip_bfloat16*)split;

  conv_split_k<<<dim3(1024), 256, 0, stream>>>(x, xhi, xlo);
  conv_split_k<<<dim3(1536), 256, 0, stream>>>(wat, whi, wlo);
  gemm_mfma_k<true><<<dim3(16*24), 256, 0, stream>>>(xhi, xlo, whi, wlo, qkv, TT, C3, CC);
  conv_kb_k<<<dim3(1024), 256, 0, stream>>>(qkv, kb);
  conv_ks_k<<<dim3(HH*MM/4), 256, 0, stream>>>(kst, ksb, ksn, ksnb);
  conv_bf16_k<<<dim3(512), 256, 0, stream>>>(wpr, wprb);
  attlast_mask_k<<<dim3(HH), 256, 0, stream>>>(qkv, maskb);
  knn_chunkmin_k<<<dim3(512), 256, 0, stream>>>(kb, ksb, ksnb, candb);
  knn_select_k<<<dim3(HH*TT/4), 256, 0, stream>>>(candb, qkv, kst, ksn, idxb);
  knn_apply_k<<<dim3(HH*TT/4), 256, 0, stream>>>(qkv, kst, vst, idxb, maskb, vnew);
  vtrans_k<<<dim3(32, HH), 256, 0, stream>>>(vnew, vbT);
  attn_mfma_k<<<dim3(16, HH), 256, 0, stream>>>(qkv, kb, vbT, yb);
  gemm_mfma_k<false><<<dim3(16*8), 256, 0, stream>>>(yb, nullptr, wprb, nullptr, out, TT, CC, CC);
}

// Round 5
// 314.240 us; speedup vs baseline: 5.7596x; 1.1214x over previous
//
#include <hip/hip_runtime.h>
#include <hip/hip_bf16.h>
#include <math.h>

#define TT 2048
#define CC 1024
#define HH 16
#define DDIM 64
#define MM 8192
#define C3 3072
#define SBIAS 256.0f

typedef __bf16 bf16x8 __attribute__((ext_vector_type(8)));
typedef float f32x4 __attribute__((ext_vector_type(4)));

__device__ __forceinline__ float waveReduceSum(float v) {
#pragma unroll
  for (int off = 32; off > 0; off >>= 1) v += __shfl_xor(v, off, 64);
  return v;
}
__device__ __forceinline__ unsigned umn(unsigned a, unsigned b){ return a<b?a:b; }
__device__ __forceinline__ unsigned umx(unsigned a, unsigned b){ return a>b?a:b; }

// async global->LDS, 16B per lane (linear dest, per-lane src carries swizzle)
__device__ __forceinline__ void gload16(const void* g, void* l) {
  __builtin_amdgcn_global_load_lds(
      (const __attribute__((address_space(1))) unsigned int*)g,
      (__attribute__((address_space(3))) unsigned int*)l, 16, 0, 0);
}

// ---------------- conversions ----------------
__global__ __launch_bounds__(256) void conv_split_k(const float* __restrict__ src,
    __hip_bfloat16* __restrict__ hi, __hip_bfloat16* __restrict__ lo)
{
  size_t i = (size_t)blockIdx.x*256 + threadIdx.x;
  const float4* p = (const float4*)(src + i*8);
  float4 a = p[0], b = p[1];
  float v[8] = {a.x,a.y,a.z,a.w,b.x,b.y,b.z,b.w};
  bf16x8 H, L;
#pragma unroll
  for (int e = 0; e < 8; ++e) {
    __bf16 hb = (__bf16)v[e];
    H[e] = hb;
    L[e] = (__bf16)(v[e] - (float)hb);
  }
  *reinterpret_cast<bf16x8*>(hi + i*8) = H;
  *reinterpret_cast<bf16x8*>(lo + i*8) = L;
}

__global__ __launch_bounds__(256) void conv_bf16_k(const float* __restrict__ src,
    __hip_bfloat16* __restrict__ dst)
{
  size_t i = (size_t)blockIdx.x*256 + threadIdx.x;
  const float4* p = (const float4*)(src + i*8);
  float4 a = p[0], b = p[1];
  float v[8] = {a.x,a.y,a.z,a.w,b.x,b.y,b.z,b.w};
  bf16x8 H;
#pragma unroll
  for (int e = 0; e < 8; ++e) H[e] = (__bf16)v[e];
  *reinterpret_cast<bf16x8*>(dst + i*8) = H;
}

__global__ __launch_bounds__(256) void conv_ks_k(const float* __restrict__ ks,
    __hip_bfloat16* __restrict__ ksb, float* __restrict__ ksn, float* __restrict__ ksnb)
{
  int row = blockIdx.x*4 + (threadIdx.x>>6);   // HH*MM rows
  int lane = threadIdx.x & 63;
  float v = ks[(size_t)row*64 + lane];
  float sq = waveReduceSum(v*v);
  ksb[(size_t)row*64 + lane] = __float2bfloat16(v);
  if (lane == 0) { ksn[row] = sq; ksnb[row] = sq + SBIAS; }
}

__global__ __launch_bounds__(256) void conv_kb_k(const float* __restrict__ qkv,
    __hip_bfloat16* __restrict__ kb)
{
  int e = blockIdx.x*256 + threadIdx.x;
  int dg = e & 7; int t = (e>>3) & (TT-1); int h = e >> 14;
  const float* src = qkv + (size_t)t*C3 + CC + h*64 + dg*8;
  __hip_bfloat16* dst = kb + ((size_t)(h*TT + t)*64 + dg*8);
#pragma unroll
  for (int i = 0; i < 8; ++i) dst[i] = __float2bfloat16(src[i]);
}

__global__ __launch_bounds__(256) void vtrans_k(const float* __restrict__ vnew,
    __hip_bfloat16* __restrict__ vbT)
{
  __shared__ float tbuf[64][65];
  const int h = blockIdx.y, t0 = blockIdx.x*64, tid = threadIdx.x;
#pragma unroll
  for (int r = 0; r < 16; ++r) {
    int e = r*256 + tid; int row = e>>6, dv = e&63;
    tbuf[row][dv] = vnew[((size_t)h*TT + t0 + row)*64 + dv];
  }
  __syncthreads();
#pragma unroll
  for (int r = 0; r < 16; ++r) {
    int e = r*256 + tid; int dv = e>>6, tt = e&63;
    vbT[((size_t)h*64 + dv)*TT + t0 + tt] = __float2bfloat16(tbuf[tt][dv]);
  }
}

// ---------------- MFMA GEMM: C[m][n] = sum_k A[m][k]*B[n][k] ----------------
template<bool SPLIT>
__global__ __launch_bounds__(256) void gemm_mfma_k(
    const __hip_bfloat16* __restrict__ Ah, const __hip_bfloat16* __restrict__ Al,
    const __hip_bfloat16* __restrict__ Bh, const __hip_bfloat16* __restrict__ Bl,
    float* __restrict__ Cc, int M, int N, int K)
{
  __shared__ __align__(16) char lds[2][32768];
  const int tid = threadIdx.x;
  const int nbx = N >> 7;
  const int by = blockIdx.x / nbx, bx = blockIdx.x - by*nbx;
  const int m0 = by << 7, n0 = bx << 7;
  const int w = tid >> 6;
  const int l = tid & 63;
  const int wslot = w << 6;
  const int wi = w >> 1, wj = w & 1;
  const int fr = l & 15, fo = l >> 4;
  const int kw = SPLIT ? 32 : 64;
  const int nsteps = K / kw;

  f32x4 acc[4][4];
#pragma unroll
  for (int i = 0; i < 4; ++i)
#pragma unroll
    for (int j = 0; j < 4; ++j) acc[i][j] = f32x4{0.f,0.f,0.f,0.f};

  int srow[4], schg[4];
#pragma unroll
  for (int r = 0; r < 4; ++r) {
    int s = r*256 + tid;
    srow[r] = s >> 3;
    schg[r] = (s & 7) ^ (srow[r] & 7);
  }

  auto stageAB = [&](int buf, int st) {
    const int k0 = st * kw;
#pragma unroll
    for (int r = 0; r < 4; ++r) {
      const __hip_bfloat16 *pa, *pb;
      if (SPLIT) {
        pa = (schg[r] < 4 ? Ah : Al) + (size_t)(m0+srow[r])*K + k0 + (schg[r]&3)*8;
        pb = (schg[r] < 4 ? Bh : Bl) + (size_t)(n0+srow[r])*K + k0 + (schg[r]&3)*8;
      } else {
        pa = Ah + (size_t)(m0+srow[r])*K + k0 + schg[r]*8;
        pb = Bh + (size_t)(n0+srow[r])*K + k0 + schg[r]*8;
      }
      gload16(pa, lds[buf] + (r*256 + wslot)*16);
      gload16(pb, lds[buf] + 16384 + (r*256 + wslot)*16);
    }
  };

  stageAB(0, 0);
  __syncthreads();

  for (int st = 0; st < nsteps; ++st) {
    const int buf = st & 1;
    if (st + 1 < nsteps) stageAB(buf ^ 1, st + 1);
    char* ldsb = lds[buf];

    if (SPLIT) {
      bf16x8 bhf[4], blf[4];
#pragma unroll
      for (int j = 0; j < 4; ++j) {
        int row = wj*64 + j*16 + fr;
        bhf[j] = *(const bf16x8*)(ldsb + 16384 + row*128 + ((fo     ^ (row&7))*16));
        blf[j] = *(const bf16x8*)(ldsb + 16384 + row*128 + (((4+fo) ^ (row&7))*16));
      }
#pragma unroll
      for (int i = 0; i < 4; ++i) {
        int row = wi*64 + i*16 + fr;
        bf16x8 ah = *(const bf16x8*)(ldsb + row*128 + ((fo     ^ (row&7))*16));
        bf16x8 al = *(const bf16x8*)(ldsb + row*128 + (((4+fo) ^ (row&7))*16));
#pragma unroll
        for (int j = 0; j < 4; ++j) {
          acc[i][j] = __builtin_amdgcn_mfma_f32_16x16x32_bf16(al, bhf[j], acc[i][j], 0,0,0);
          acc[i][j] = __builtin_amdgcn_mfma_f32_16x16x32_bf16(ah, blf[j], acc[i][j], 0,0,0);
          acc[i][j] = __builtin_amdgcn_mfma_f32_16x16x32_bf16(ah, bhf[j], acc[i][j], 0,0,0);
        }
      }
    } else {
#pragma unroll
      for (int kk = 0; kk < 2; ++kk) {
        bf16x8 bf[4];
#pragma unroll
        for (int j = 0; j < 4; ++j) {
          int row = wj*64 + j*16 + fr;
          bf[j] = *(const bf16x8*)(ldsb + 16384 + row*128 + (((kk*4+fo) ^ (row&7))*16));
        }
#pragma unroll
        for (int i = 0; i < 4; ++i) {
          int row = wi*64 + i*16 + fr;
          bf16x8 af = *(const bf16x8*)(ldsb + row*128 + (((kk*4+fo) ^ (row&7))*16));
#pragma unroll
          for (int j = 0; j < 4; ++j)
            acc[i][j] = __builtin_amdgcn_mfma_f32_16x16x32_bf16(af, bf[j], acc[i][j], 0,0,0);
        }
      }
    }
    __syncthreads();
  }

  // epilogue: per-wave LDS transpose -> float4 row stores
  float* ep = (float*)((char*)lds + (size_t)w*8704);
#pragma unroll
  for (int pass = 0; pass < 2; ++pass) {
#pragma unroll
    for (int ii = 0; ii < 2; ++ii) {
      int i = pass*2 + ii;
#pragma unroll
      for (int j = 0; j < 4; ++j)
#pragma unroll
        for (int e = 0; e < 4; ++e)
          ep[(ii*16 + fo*4 + e)*68 + j*16 + fr] = acc[i][j][e];
    }
#pragma unroll
    for (int eidx = 0; eidx < 8; ++eidx) {
      int fi = eidx*64 + l;
      int row = fi >> 4, c4 = fi & 15;
      float4 v4 = *(const float4*)(ep + row*68 + c4*4);
      *(float4*)(Cc + (size_t)(m0 + wi*64 + pass*32 + row)*N + n0 + wj*64 + c4*4) = v4;
    }
  }
}

// ---------------- exact fp32 softmax of last attention row -> mask ----------------
__global__ __launch_bounds__(256) void attlast_mask_k(const float* __restrict__ qkv, int* __restrict__ mask)
{
  const int h = blockIdx.x;
  __shared__ float ql[64];
  __shared__ float lg[TT];
  __shared__ float red[256];
  const int tid = threadIdx.x;
  if (tid < 64) ql[tid] = qkv[(size_t)(TT-1)*C3 + h*DDIM + tid];
  __syncthreads();
  float lmax = -INFINITY;
  for (int t = tid; t < TT; t += 256) {
    const float* kr = qkv + (size_t)t*C3 + CC + h*DDIM;
    float s = 0.f;
#pragma unroll
    for (int d = 0; d < 64; ++d) s += ql[d] * kr[d];
    s *= 0.125f;
    lg[t] = s;
    lmax = fmaxf(lmax, s);
  }
  red[tid] = lmax; __syncthreads();
  for (int off = 128; off > 0; off >>= 1) { if (tid < off) red[tid] = fmaxf(red[tid], red[tid+off]); __syncthreads(); }
  float mx = red[0];
  __syncthreads();
  float ls = 0.f;
  for (int t = tid; t < TT; t += 256) { float e = expf(lg[t]-mx); lg[t] = e; ls += e; }
  red[tid] = ls; __syncthreads();
  for (int off = 128; off > 0; off >>= 1) { if (tid < off) red[tid] += red[tid+off]; __syncthreads(); }
  float Z = red[0];
  for (int t = tid; t < TT; t += 256) mask[h*TT + t] = (lg[t]/Z >= 1.220703125e-4f) ? 1 : 0;
}

// ---------------- phase A: bf16 MFMA scoring + per-cell top-4 chunk-mins ----------------
// packed cand = (scorebits & 0xFFFFF800) | (cr<<7) | tile   (self-describing chunk)
__global__ __launch_bounds__(256) void knn_chunkmin_k(
    const __hip_bfloat16* __restrict__ kb, const __hip_bfloat16* __restrict__ ksb,
    const float* __restrict__ ksnb, unsigned int* __restrict__ cand)
{
  __shared__ __align__(16) char lds[2*8192];
  const int tid = threadIdx.x;
  const int bid = blockIdx.x;
  const int orig = (bid & 7)*64 + (bid >> 3);
  const int h  = orig >> 5;
  const int n0 = (orig & 31) * 64;
  const int w  = tid >> 6;
  const int l  = tid & 63;
  const int cr = l & 15, hi = l >> 4;
  const unsigned crbits = (unsigned)cr << 7;

  bf16x8 af0, af1;
  {
    const __hip_bfloat16* kbh = kb + (size_t)h*TT*64 + (size_t)(n0 + w*16 + cr)*64;
    af0 = *reinterpret_cast<const bf16x8*>(kbh + 0*32 + hi*8);
    af1 = *reinterpret_cast<const bf16x8*>(kbh + 1*32 + hi*8);
  }
  const __hip_bfloat16* ksbh = ksb + (size_t)h*MM*64;
  const float* ksnh = ksnb + (size_t)h*MM;

  const int c0 = tid*2, c1 = tid*2 + 1;
  const int wb0 = (c0>>3)*128 + (((c0&7) ^ ((c0>>3)&7))*16);
  const int wb1 = (c1>>3)*128 + (((c1&7) ^ ((c1>>3)&7))*16);
  const int rb0 = (l&15)*128 + (((0 + hi) ^ (l&7))*16);
  const int rb1 = (l&15)*128 + (((4 + hi) ^ (l&7))*16);

  unsigned cnd[4][4];
#pragma unroll
  for (int i = 0; i < 4; ++i)
#pragma unroll
    for (int c = 0; c < 4; ++c) cnd[i][c] = 0xFFFFFFFFu;

  uint4 r0, r1;
  {
    const uint4* g = reinterpret_cast<const uint4*>(ksbh);
    r0 = g[c0]; r1 = g[c1];
    *reinterpret_cast<uint4*>(lds + wb0) = r0;
    *reinterpret_cast<uint4*>(lds + wb1) = r1;
  }

  for (int tt = 0; tt < 128; ++tt) {
    __syncthreads();
    const int buf = tt & 1;
    char* ldsb = lds + buf*8192;
    if (tt + 1 < 128) {
      const uint4* g = reinterpret_cast<const uint4*>(ksbh + (size_t)(tt+1)*64*64);
      r0 = g[c0]; r1 = g[c1];
    }
    float kn0 = ksnh[tt*64 +  0 + cr];
    float kn1 = ksnh[tt*64 + 16 + cr];
    float kn2 = ksnh[tt*64 + 32 + cr];
    float kn3 = ksnh[tt*64 + 48 + cr];

    f32x4 acc[4];
#pragma unroll
    for (int b = 0; b < 4; ++b) {
      bf16x8 bf0 = *reinterpret_cast<const bf16x8*>(ldsb + b*2048 + rb0);
      bf16x8 bf1 = *reinterpret_cast<const bf16x8*>(ldsb + b*2048 + rb1);
      f32x4 z = {0.f, 0.f, 0.f, 0.f};
      z = __builtin_amdgcn_mfma_f32_16x16x32_bf16(af0, bf0, z, 0, 0, 0);
      z = __builtin_amdgcn_mfma_f32_16x16x32_bf16(af1, bf1, z, 0, 0, 0);
      acc[b] = z;
    }
#pragma unroll
    for (int i = 0; i < 4; ++i) {
      float s0 = fmaf(acc[0][i], -2.f, kn0);
      float s1 = fmaf(acc[1][i], -2.f, kn1);
      float s2 = fmaf(acc[2][i], -2.f, kn2);
      float s3 = fmaf(acc[3][i], -2.f, kn3);
      float m4 = fminf(fminf(s0, s1), fminf(s2, s3));
      unsigned x = (__float_as_uint(m4) & 0xFFFFF800u) | crbits | (unsigned)tt;
      unsigned tmp;
      tmp = umn(cnd[i][0], x); x = umx(cnd[i][0], x); cnd[i][0] = tmp;
      tmp = umn(cnd[i][1], x); x = umx(cnd[i][1], x); cnd[i][1] = tmp;
      tmp = umn(cnd[i][2], x); x = umx(cnd[i][2], x); cnd[i][2] = tmp;
      cnd[i][3] = umn(cnd[i][3], x);
    }
    if (tt + 1 < 128) {
      char* ldsn = lds + (buf^1)*8192;
      *reinterpret_cast<uint4*>(ldsn + wb0) = r0;
      *reinterpret_cast<uint4*>(ldsn + wb1) = r1;
    }
  }

#pragma unroll
  for (int i = 0; i < 4; ++i) {
    int n = n0 + w*16 + hi*4 + i;
    reinterpret_cast<uint4*>(cand)[(size_t)(h*TT + n)*16 + cr] =
        make_uint4(cnd[i][0], cnd[i][1], cnd[i][2], cnd[i][3]);
  }
}

// ---------------- fused phase B: top-8 chunks -> fp32 rescore -> top-4 -> v_new ----------------
// one wave per row; bitonic sorts replace serialized wave reductions.
__global__ __launch_bounds__(256) void knn_fused_k(
    const unsigned int* __restrict__ cand, const float* __restrict__ qkv,
    const float* __restrict__ kstore, const float* __restrict__ vstore,
    const float* __restrict__ ksn, const int* __restrict__ mask,
    float* __restrict__ vnew)
{
  const int row = blockIdx.x*4 + (threadIdx.x>>6);
  const int l = threadIdx.x & 63;
  const int h = row >> 11, t = row & (TT-1);
  const float* base = qkv + (size_t)t*C3 + h*64;
  float vh = base[2*CC + l];
  float* outp = vnew + (size_t)row*64;
  if (!mask[row]) { outp[l] = vh; return; }

  // stage 1: top-8 chunks of 64 packed values (ascending bitonic sort)
  unsigned v = cand[(size_t)row*64 + l];
#pragma unroll
  for (int k = 2; k <= 64; k <<= 1)
#pragma unroll
    for (int j = k>>1; j > 0; j >>= 1) {
      unsigned o = __shfl_xor(v, j, 64);
      bool takeMin = ((l & j) == 0) == ((l & k) == 0);
      v = (takeMin == (o < v)) ? o : v;
    }

  // stage 2: expand 8 chunks -> 32 candidates; exact fp32 k-dot, 2 lanes/cand
  const int c = l >> 1;
  const int b = c & 3;
  unsigned vc = __shfl(v, c >> 2, 64);
  const int m = ((int)(vc & 127u))*64 + b*16 + (int)((vc >> 7) & 15u);
  const int p = l & 1;
  {
    const float* kq = base + CC + p*32;
    const float* ksr = kstore + ((size_t)h*MM + m)*64 + p*32;
    float dp = 0.f;
#pragma unroll
    for (int i = 0; i < 8; ++i) {
      float4 a = *(const float4*)(kq + i*4);
      float4 bb = *(const float4*)(ksr + i*4);
      dp = fmaf(a.x,bb.x, fmaf(a.y,bb.y, fmaf(a.z,bb.z, fmaf(a.w,bb.w, dp))));
    }
    dp += __shfl_xor(dp, 1, 64);
    float s = ksn[(size_t)h*MM + m] - 2.f*dp;
    unsigned u = __float_as_uint(s);
    unsigned skey = u ^ (unsigned)(((int)u >> 31) | 0x80000000);
    unsigned khi = (p == 0) ? skey : 0xFFFFFFFFu;
    unsigned klo = (p == 0) ? (unsigned)m : 0xFFFFFFFFu;
    // (score, m) lexicographic ascending bitonic sort
#pragma unroll
    for (int k = 2; k <= 64; k <<= 1)
#pragma unroll
      for (int j = k>>1; j > 0; j >>= 1) {
        unsigned oh = __shfl_xor(khi, j, 64);
        unsigned ol = __shfl_xor(klo, j, 64);
        bool takeMin = ((l & j) == 0) == ((l & k) == 0);
        bool oLess = (oh < khi) || (oh == khi && ol < klo);
        if (takeMin == oLess) { khi = oh; klo = ol; }
      }
    v = klo;   // reuse reg: sorted m's (lanes 0..3 = top-4)
  }

  // stage 3: apply -- softmax over {self, m0..m3} with q-dots (8-lane groups)
  const int m0 = (int)__shfl(v, 0, 64);
  const int m1 = (int)__shfl(v, 1, 64);
  const int m2 = (int)__shfl(v, 2, 64);
  const int m3 = (int)__shfl(v, 3, 64);
  const int g = l >> 3, gl = l & 7;
  float dq = 0.f;
  if (g < 5) {
    int msel = (g == 0) ? m0 : (g == 1) ? m1 : (g == 2) ? m2 : m3;
    const float* qrow = base + gl*8;
    const float* kr = (g < 4) ? (kstore + ((size_t)h*MM + msel)*64 + gl*8)
                              : (base + CC + gl*8);
    float4 a0 = *(const float4*)(qrow);
    float4 a1 = *(const float4*)(qrow + 4);
    float4 b0 = *(const float4*)(kr);
    float4 b1 = *(const float4*)(kr + 4);
    dq = a0.x*b0.x + a0.y*b0.y + a0.z*b0.z + a0.w*b0.w
       + a1.x*b1.x + a1.y*b1.y + a1.z*b1.z + a1.w*b1.w;
  }
  dq += __shfl_xor(dq, 1, 64);
  dq += __shfl_xor(dq, 2, 64);
  dq += __shfl_xor(dq, 4, 64);
  float d0 = __shfl(dq,  0, 64)*0.125f;
  float d1 = __shfl(dq,  8, 64)*0.125f;
  float d2 = __shfl(dq, 16, 64)*0.125f;
  float d3 = __shfl(dq, 24, 64)*0.125f;
  float d4 = __shfl(dq, 32, 64)*0.125f;   // q . k_self
  float mx = fmaxf(fmaxf(fmaxf(d0,d1),fmaxf(d2,d3)),d4);
  float w0 = expf(d0-mx), w1 = expf(d1-mx), w2 = expf(d2-mx),
        w3 = expf(d3-mx), w4 = expf(d4-mx);
  float Z = w0+w1+w2+w3+w4;
  float vv = w4*vh
           + w0*vstore[((size_t)h*MM+m0)*64 + l]
           + w1*vstore[((size_t)h*MM+m1)*64 + l]
           + w2*vstore[((size_t)h*MM+m2)*64 + l]
           + w3*vstore[((size_t)h*MM+m3)*64 + l];
  outp[l] = 0.5f*(vv/Z) + 0.5f*vh;
}

// ---------------- bf16 MFMA causal flash attention (2-phase gload_lds pipeline) ----------------
__global__ __launch_bounds__(256) void attn_mfma_k(
    const float* __restrict__ qkv, const __hip_bfloat16* __restrict__ kb,
    const __hip_bfloat16* __restrict__ vbT, __hip_bfloat16* __restrict__ yb)
{
  __shared__ __align__(16) char lds[40960];
  const int h = blockIdx.y, bx = blockIdx.x, tid = threadIdx.x;
  const int w = tid>>6, l = tid&63, fr = l&15, fo = l>>4;
  const int wslot = w << 6;
  const __hip_bfloat16* kbh = kb + (size_t)h*TT*64;
  const __hip_bfloat16* vbh = vbT + (size_t)h*64*TT;
  char* Pt = lds + 32768 + w*2048;

  int srow[2], schg[2];
#pragma unroll
  for (int r = 0; r < 2; ++r) {
    int s = r*256 + tid;
    srow[r] = s >> 3;
    schg[r] = (s & 7) ^ (srow[r] & 7);
  }

  auto stageKV = [&](int buf, int kt) {
#pragma unroll
    for (int r = 0; r < 2; ++r) {
      gload16(kbh + (size_t)(kt*64 + srow[r])*64 + schg[r]*8,
              lds + buf*16384 + (r*256 + wslot)*16);
      gload16(vbh + (size_t)srow[r]*TT + kt*64 + schg[r]*8,
              lds + buf*16384 + 8192 + (r*256 + wslot)*16);
    }
  };

  for (int half = 0; half < 2; ++half) {
    const int qblk = half ? (31 - bx) : bx;
    const int q0 = qblk * 64;
    bf16x8 qa[2];
    {
      const float* qrow = qkv + (size_t)(q0 + w*16 + fr)*C3 + h*64;
#pragma unroll
      for (int kk = 0; kk < 2; ++kk) {
        float4 u0 = *(const float4*)(qrow + kk*32 + fo*8);
        float4 u1 = *(const float4*)(qrow + kk*32 + fo*8 + 4);
        bf16x8 t;
        t[0]=(__bf16)u0.x; t[1]=(__bf16)u0.y; t[2]=(__bf16)u0.z; t[3]=(__bf16)u0.w;
        t[4]=(__bf16)u1.x; t[5]=(__bf16)u1.y; t[6]=(__bf16)u1.z; t[7]=(__bf16)u1.w;
        qa[kk] = t;
      }
    }
    float mrow[4], lsum[4];
    f32x4 oacc[4];
#pragma unroll
    for (int e = 0; e < 4; ++e) { mrow[e] = -INFINITY; lsum[e] = 0.f; }
#pragma unroll
    for (int jv = 0; jv < 4; ++jv) oacc[jv] = f32x4{0.f,0.f,0.f,0.f};

    const int ntiles = qblk + 1;
    stageKV(0, 0);
    __syncthreads();

    for (int kt = 0; kt < ntiles; ++kt) {
      const int buf = kt & 1;
      if (kt + 1 < ntiles) stageKV(buf ^ 1, kt + 1);
      char* Kt = lds + buf*16384;
      char* Vt = Kt + 8192;

      f32x4 sv[4];
#pragma unroll
      for (int j = 0; j < 4; ++j) {
        int row = j*16 + fr;
        bf16x8 k0f = *(const bf16x8*)(Kt + row*128 + ((fo     ^ (row&7))*16));
        bf16x8 k1f = *(const bf16x8*)(Kt + row*128 + (((4+fo) ^ (row&7))*16));
        f32x4 z = {0.f,0.f,0.f,0.f};
        z = __builtin_amdgcn_mfma_f32_16x16x32_bf16(qa[0], k0f, z, 0,0,0);
        z = __builtin_amdgcn_mfma_f32_16x16x32_bf16(qa[1], k1f, z, 0,0,0);
        sv[j] = z;
      }
      if (kt == qblk) {
#pragma unroll
        for (int j = 0; j < 4; ++j)
#pragma unroll
          for (int e = 0; e < 4; ++e)
            sv[j][e] = (j*16 + fr <= w*16 + fo*4 + e) ? sv[j][e]*0.125f : -INFINITY;
      } else {
#pragma unroll
        for (int j = 0; j < 4; ++j)
#pragma unroll
          for (int e = 0; e < 4; ++e) sv[j][e] *= 0.125f;
      }
      float rmax[4];
#pragma unroll
      for (int e = 0; e < 4; ++e)
        rmax[e] = fmaxf(fmaxf(sv[0][e], sv[1][e]), fmaxf(sv[2][e], sv[3][e]));
#pragma unroll
      for (int off = 1; off < 16; off <<= 1)
#pragma unroll
        for (int e = 0; e < 4; ++e) rmax[e] = fmaxf(rmax[e], __shfl_xor(rmax[e], off, 64));
      float scl[4];
#pragma unroll
      for (int e = 0; e < 4; ++e) {
        float mn = fmaxf(mrow[e], rmax[e]);
        scl[e] = __expf(mrow[e] - mn);
        mrow[e] = mn;
      }
      float rsum[4] = {0.f,0.f,0.f,0.f};
#pragma unroll
      for (int j = 0; j < 4; ++j) {
        int chunkbase = j*2 + (fr>>3);
        int kvoff = (fr&7)*2;
#pragma unroll
        for (int e = 0; e < 4; ++e) {
          float p = __expf(sv[j][e] - mrow[e]);
          rsum[e] += p;
          int qloc = fo*4 + e;
          *(__bf16*)(Pt + qloc*128 + ((chunkbase ^ (qloc&7))*16) + kvoff) = (__bf16)p;
        }
      }
#pragma unroll
      for (int off = 1; off < 16; off <<= 1)
#pragma unroll
        for (int e = 0; e < 4; ++e) rsum[e] += __shfl_xor(rsum[e], off, 64);
#pragma unroll
      for (int e = 0; e < 4; ++e) lsum[e] = lsum[e]*scl[e] + rsum[e];
#pragma unroll
      for (int jv = 0; jv < 4; ++jv)
#pragma unroll
        for (int e = 0; e < 4; ++e) oacc[jv][e] *= scl[e];

      bf16x8 pa0 = *(const bf16x8*)(Pt + fr*128 + ((fo     ^ (fr&7))*16));
      bf16x8 pa1 = *(const bf16x8*)(Pt + fr*128 + (((4+fo) ^ (fr&7))*16));
#pragma unroll
      for (int jv = 0; jv < 4; ++jv) {
        int row = jv*16 + fr;
        bf16x8 v0f = *(const bf16x8*)(Vt + row*128 + ((fo     ^ (row&7))*16));
        bf16x8 v1f = *(const bf16x8*)(Vt + row*128 + (((4+fo) ^ (row&7))*16));
        oacc[jv] = __builtin_amdgcn_mfma_f32_16x16x32_bf16(pa0, v0f, oacc[jv], 0,0,0);
        oacc[jv] = __builtin_amdgcn_mfma_f32_16x16x32_bf16(pa1, v1f, oacc[jv], 0,0,0);
      }
      __syncthreads();
    }
#pragma unroll
    for (int jv = 0; jv < 4; ++jv)
#pragma unroll
      for (int e = 0; e < 4; ++e) {
        int t = q0 + w*16 + fo*4 + e;
        yb[(size_t)t*CC + h*64 + jv*16 + fr] = __float2bfloat16(oacc[jv][e] / lsum[e]);
      }
  }
}

extern "C" void kernel_launch(void* const* d_in, const int* in_sizes, int n_in,
                              void* d_out, int out_size, void* d_ws, size_t ws_size,
                              hipStream_t stream) {
  const float* x   = (const float*)d_in[0];
  const float* wat = (const float*)d_in[1];
  const float* wpr = (const float*)d_in[2];
  const float* kst = (const float*)d_in[3];
  const float* vst = (const float*)d_in[4];
  float* out = (float*)d_out;

  float* ws    = (float*)d_ws;
  float* qkv   = ws;                                   // 6291456
  float* ksn   = qkv + (size_t)6291456;                // 131072
  float* ksnb  = ksn + 131072;                         // 131072
  int*   idxb  = (int*)(ksnb + 131072);                // 131072 (reserved)
  int*   maskb = idxb + 131072;                        // 32768
  __hip_bfloat16* kb = (__hip_bfloat16*)(maskb + 32768);       // 2097152 bf16
  float* candRegion = (float*)kb + 1048576;            // 2097152 (cand u32 / vnew f32)
  unsigned int* candb = (unsigned int*)candRegion;
  float* vnew = candRegion;                            // alias: fused kernel reads cand[row] then writes vnew[row]
  __hip_bfloat16* vbT = (__hip_bfloat16*)(candRegion + 2097152); // 2097152 bf16
  float* split = candRegion + 2097152 + 1048576;       // 5242880 fs region
  __hip_bfloat16* xhi = (__hip_bfloat16*)split;
  __hip_bfloat16* xlo = xhi + 2097152;
  __hip_bfloat16* whi = xlo + 2097152;
  __hip_bfloat16* wlo = whi + 3145728;
  __hip_bfloat16* ksb  = (__hip_bfloat16*)split;
  __hip_bfloat16* wprb = ksb + 8388608;
  __hip_bfloat16* yb   = (__hip_bfloat16*)split;

  conv_split_k<<<dim3(1024), 256, 0, stream>>>(x, xhi, xlo);
  conv_split_k<<<dim3(1536), 256, 0, stream>>>(wat, whi, wlo);
  gemm_mfma_k<true><<<dim3(16*24), 256, 0, stream>>>(xhi, xlo, whi, wlo, qkv, TT, C3, CC);
  conv_kb_k<<<dim3(1024), 256, 0, stream>>>(qkv, kb);
  conv_ks_k<<<dim3(HH*MM/4), 256, 0, stream>>>(kst, ksb, ksn, ksnb);
  conv_bf16_k<<<dim3(512), 256, 0, stream>>>(wpr, wprb);
  attlast_mask_k<<<dim3(HH), 256, 0, stream>>>(qkv, maskb);
  knn_chunkmin_k<<<dim3(512), 256, 0, stream>>>(kb, ksb, ksnb, candb);
  knn_fused_k<<<dim3(HH*TT/4), 256, 0, stream>>>(candb, qkv, kst, vst, ksn, maskb, vnew);
  vtrans_k<<<dim3(32, HH), 256, 0, stream>>>(vnew, vbT);
  attn_mfma_k<<<dim3(16, HH), 256, 0, stream>>>(qkv, kb, vbT, yb);
  gemm_mfma_k<false><<<dim3(16*8), 256, 0, stream>>>(yb, nullptr, wprb, nullptr, out, TT, CC, CC);
}